// Round 5
// baseline (208.358 us; speedup 1.0000x reference)
//
#include <hip/hip_runtime.h>

typedef unsigned short ushort_t;

#define NVOX 4096
#define NSV  256
#define XD   128
#define YD   128
#define ZD   16
#define CD   128
#define NCD  20
#define HD   8
#define DHD  16
#define MAPN 524288
#define EPSF 1e-5f

// ---- fp32 arena offsets (floats) ----
#define OF_FEAT 0
#define OF_CW1  524288
#define OF_CB1  540672
#define OF_CG1  540800
#define OF_CBE1 540928
#define OF_CW2  541056
#define OF_CB2  557440
#define OF_PW1  557568
#define OF_PB1  557760
#define OF_PG1  557824
#define OF_PBE1 557888
#define OF_PW2  557952
#define OF_PB2  558016
#define OF_WQ   558080
#define OF_BQ   574464
#define OF_WK   574592
#define OF_BK   590976
#define OF_WV   591104
#define OF_BV   607488
#define OF_WO   607616
#define OF_BO   624000
#define OF_LNG  624128
#define OF_LNB  624256
#define OF_SEGW 624384
#define OF_SEGB 693504
#define ARENA_N 693568
#define TOTCVT  624341   /* segw excluded (transposed separately) */

__device__ __forceinline__ float bf2f(const ushort_t* p){
  return __uint_as_float(((unsigned)(*p)) << 16);
}
__device__ __forceinline__ ushort_t f2bf(float f){
  unsigned u = __float_as_uint(f);
  u += 0x7fffu + ((u >> 16) & 1u);
  return (ushort_t)(u >> 16);
}
__device__ __forceinline__ float unlo(unsigned u){ return __uint_as_float(u << 16); }
__device__ __forceinline__ float unhi(unsigned u){ return __uint_as_float(u & 0xffff0000u); }

struct SrcPtrs { const void* p[25]; };

__device__ const int g_cnt[25] = {524288,16384,128,128,128,16384,128,192,64,64,64,64,1,
                                  16384,128,16384,128,16384,128,16384,128,128,128,0,20};
__device__ const int g_off[25] = {OF_FEAT,OF_CW1,OF_CB1,OF_CG1,OF_CBE1,OF_CW2,OF_CB2,
                                  OF_PW1,OF_PB1,OF_PG1,OF_PBE1,OF_PW2,OF_PB2,
                                  OF_WQ,OF_BQ,OF_WK,OF_BK,OF_WV,OF_BV,OF_WO,OF_BO,
                                  OF_LNG,OF_LNB,OF_SEGW,OF_SEGB};

__device__ __forceinline__ float ldi(const void* p, int off, int fl){
  return fl ? bf2f((const ushort_t*)p + off) : ((const float*)p)[off];
}

struct SPREP {
  float frows[16][CD];     // 8 KB
  float qpart[2][16][CD];  // 16 KB
  float part[8][CD];       // 4 KB
  float cfs[CD];           // 0.5 KB
  float gpart[8][CD];      // 4 KB
};
union __align__(16) UPREP { SPREP sv; int smom[18]; };

// ========== KPREP (512 threads) ==========
__global__ __launch_bounds__(512) void kprep(SrcPtrs sp, const int* idx, int* flag,
    float* arena, float* wt, int* map, float* afold_g, float* scfold_g,
    float* qb, float* t1T)
{
  __shared__ UPREP sm;
  __shared__ int sm_flag;
  int t = threadIdx.x, b = blockIdx.x;
  if (t < 64){
    const ushort_t* f16 = (const ushort_t*)sp.p[0];
    unsigned u = f16[2*t];
    int e = (u >> 7) & 0xFF;
    int sane = (u == 0 || (e >= 90 && e <= 150)) ? 1 : 0;
    unsigned long long bl = __ballot(sane);
    if (t == 0) sm_flag = (__popcll(bl) >= 48) ? 1 : 0;
  }
  __syncthreads();
  const int fl = sm_flag;

  if (b < 255){
    int gid = b*512 + t;
    const int GS = 255*512;
    if (gid == 0) *flag = fl;
    for (int k=gid; k<MAPN; k+=GS) map[k] = -1;
    for (int el=gid; el<TOTCVT; el+=GS){
      int s=0, rem=el;
      while (rem >= g_cnt[s]){ rem -= g_cnt[s]; ++s; }
      arena[g_off[s]+rem] = ldi(sp.p[s], rem, fl);
    }
    for (int k=gid; k<27*NCD*CD; k+=GS){
      int nb = k/(NCD*CD); int rem = k - nb*(NCD*CD); int o = rem/CD, i = rem - o*CD;
      wt[k] = ldi(sp.p[23], nb*(CD*NCD) + i*NCD + o, fl);
    }
  } else if (b < 511){
    int sv = b - 255;
    int rb = sv*16;
    if (fl){
      const uint2* fsrc = (const uint2*)((const ushort_t*)sp.p[0] + (size_t)rb*CD);
      uint2 u = fsrc[t];
      float* dst = &sm.sv.frows[t>>5][(t&31)*4];
      dst[0]=unlo(u.x); dst[1]=unhi(u.x); dst[2]=unlo(u.y); dst[3]=unhi(u.y);
    } else {
      const float4* fsrc = (const float4*)((const float*)sp.p[0] + (size_t)rb*CD);
      ((float4*)sm.sv.frows)[t] = fsrc[t];
    }
    __syncthreads();
    // ---- q-proj: thread = (c8:16, row:16, khalf:2)
    {
      int c8 = (t&15)*8, r = (t>>4)&15, kh = t>>8;
      int i0 = kh*64;
      float acc[8] = {0.f,0.f,0.f,0.f,0.f,0.f,0.f,0.f};
      if (fl){
        const ushort_t* wqp = (const ushort_t*)sp.p[13];
        #pragma unroll 4
        for (int i=i0; i<i0+64; ++i){
          uint4 w4 = *(const uint4*)(wqp + (size_t)i*CD + c8);
          float fr = sm.sv.frows[r][i];
          acc[0] += unlo(w4.x)*fr; acc[1] += unhi(w4.x)*fr;
          acc[2] += unlo(w4.y)*fr; acc[3] += unhi(w4.y)*fr;
          acc[4] += unlo(w4.z)*fr; acc[5] += unhi(w4.z)*fr;
          acc[6] += unlo(w4.w)*fr; acc[7] += unhi(w4.w)*fr;
        }
      } else {
        const float* wqp = (const float*)sp.p[13];
        #pragma unroll 4
        for (int i=i0; i<i0+64; ++i){
          float4 wa = *(const float4*)(wqp + (size_t)i*CD + c8);
          float4 wb = *(const float4*)(wqp + (size_t)i*CD + c8 + 4);
          float fr = sm.sv.frows[r][i];
          acc[0]+=wa.x*fr; acc[1]+=wa.y*fr; acc[2]+=wa.z*fr; acc[3]+=wa.w*fr;
          acc[4]+=wb.x*fr; acc[5]+=wb.y*fr; acc[6]+=wb.z*fr; acc[7]+=wb.w*fr;
        }
      }
      #pragma unroll
      for (int j=0;j<8;++j) sm.sv.qpart[kh][r][c8+j] = acc[j];
    }
    __syncthreads();
    for (int e = t; e < 16*CD; e += 512){
      int r = e>>7, c = e&127;
      qb[(size_t)(rb+r)*CD + c] = sm.sv.qpart[0][r][c] + sm.sv.qpart[1][r][c]
                                + ldi(sp.p[14], c, fl);
    }
    // ---- segment softmax-sum: 8 waves x 2 rows
    {
      int w = t>>6, l = t&63;
      float a0 = 0.f, a1 = 0.f;
      #pragma unroll
      for (int k=0;k<2;++k){
        int r = w*2 + k;
        float f0 = sm.sv.frows[r][l];
        float f1 = sm.sv.frows[r][l+64];
        float m = fmaxf(f0,f1);
        #pragma unroll
        for (int o=32;o;o>>=1) m = fmaxf(m, __shfl_xor(m,o,64));
        float e0 = __expf(f0-m), e1 = __expf(f1-m);
        float ssum = e0+e1;
        #pragma unroll
        for (int o=32;o;o>>=1) ssum += __shfl_xor(ssum,o,64);
        float inv = 1.f/ssum;
        a0 += e0*inv; a1 += e1*inv;
      }
      sm.sv.part[w][l] = a0; sm.sv.part[w][l+64] = a1;
    }
    __syncthreads();
    if (t < CD){
      float s = 0.f;
      #pragma unroll
      for (int w=0;w<8;++w) s += sm.sv.part[w][t];
      sm.sv.cfs[t] = s;
    }
    __syncthreads();
    // ---- GEMV1: thread = (c2:64, kg:8)
    {
      int c2 = (t&63)*2, kg = t>>6;
      int i0 = kg*16;
      float a0 = 0.f, a1 = 0.f;
      if (fl){
        const ushort_t* W = (const ushort_t*)sp.p[1];
        #pragma unroll 4
        for (int i=i0; i<i0+16; ++i){
          unsigned w = *(const unsigned*)(W + (size_t)i*CD + c2);
          float cfv = sm.sv.cfs[i];
          a0 += unlo(w)*cfv; a1 += unhi(w)*cfv;
        }
      } else {
        const float* W = (const float*)sp.p[1];
        #pragma unroll 4
        for (int i=i0; i<i0+16; ++i){
          float2 w = *(const float2*)(W + (size_t)i*CD + c2);
          float cfv = sm.sv.cfs[i];
          a0 += w.x*cfv; a1 += w.y*cfv;
        }
      }
      sm.sv.gpart[kg][c2] = a0; sm.sv.gpart[kg][c2+1] = a1;
    }
    __syncthreads();
    if (t < CD){
      float s = 0.f;
      #pragma unroll
      for (int kg=0;kg<8;++kg) s += sm.sv.gpart[kg][t];
      t1T[(size_t)t*NSV + sv] = s + ldi(sp.p[2], t, fl);
    }
  } else {
    // ---- b == 511: moments + BN fold (wave-reduced, no per-lane LDS atomic storms)
    if (t < 18) sm.smom[t] = 0;
    __syncthreads();
    {
      // voxel moments
      int sacc[9] = {0,0,0,0,0,0,0,0,0};
      for (int v = t; v < NVOX; v += 512){
        int4 q = ((const int4*)idx)[v];
        sacc[0]+=q.y; sacc[1]+=q.z; sacc[2]+=q.w;
        sacc[3]+=q.y*q.y; sacc[4]+=q.z*q.z; sacc[5]+=q.w*q.w;
        sacc[6]+=q.y*q.z; sacc[7]+=q.y*q.w; sacc[8]+=q.z*q.w;
      }
      // supervoxel (cell) moments
      int um[9] = {0,0,0,0,0,0,0,0,0};
      if (t < 256){
        int4 q = ((const int4*)idx)[t*16];
        int gx=q.y>>2, gy=q.z>>2, gz=q.w>>2;
        um[0]=gx; um[1]=gy; um[2]=gz;
        um[3]=gx*gx; um[4]=gy*gy; um[5]=gz*gz;
        um[6]=gx*gy; um[7]=gx*gz; um[8]=gy*gz;
      }
      // 64-lane shuffle tree per moment, one atomic per wave per moment
      int lane = t & 63;
      #pragma unroll
      for (int i=0;i<9;++i){
        int s = sacc[i];
        int u = um[i];
        #pragma unroll
        for (int o=32;o;o>>=1){
          s += __shfl_xor(s, o, 64);
          u += __shfl_xor(u, o, 64);
        }
        if (lane == 0){
          if (s) atomicAdd(&sm.smom[9+i], s);
          if (u) atomicAdd(&sm.smom[i], u);
        }
      }
    }
    __syncthreads();
    if (t < 64){
      int* smom = sm.smom;
      double U1[3]={(double)smom[0],(double)smom[1],(double)smom[2]};
      double S1[3]={(double)smom[9],(double)smom[10],(double)smom[11]};
      double Uxx[3][3], Sxx[3][3];
      Uxx[0][0]=smom[3]; Uxx[1][1]=smom[4]; Uxx[2][2]=smom[5];
      Uxx[0][1]=Uxx[1][0]=smom[6]; Uxx[0][2]=Uxx[2][0]=smom[7]; Uxx[1][2]=Uxx[2][1]=smom[8];
      Sxx[0][0]=smom[12]; Sxx[1][1]=smom[13]; Sxx[2][2]=smom[14];
      Sxx[0][1]=Sxx[1][0]=smom[15]; Sxx[0][2]=Sxx[2][0]=smom[16]; Sxx[1][2]=Sxx[2][1]=smom[17];
      double M1[3], M2[3][3];
      for (int a=0;a<3;++a) M1[a] = 256.0*S1[a] - 4096.0*U1[a];
      for (int a=0;a<3;++a)
        for (int b2=0;b2<3;++b2)
          M2[a][b2] = 256.0*Sxx[a][b2] - S1[a]*U1[b2] - S1[b2]*U1[a] + 4096.0*Uxx[a][b2];
      double wv_[3]={(double)ldi(sp.p[7],t,fl),(double)ldi(sp.p[7],64+t,fl),(double)ldi(sp.p[7],128+t,fl)};
      double bj=(double)ldi(sp.p[8],t,fl), gj=(double)ldi(sp.p[9],t,fl), bej=(double)ldi(sp.p[10],t,fl);
      double Mw=0.0, wMw=0.0;
      for (int a=0;a<3;++a){
        Mw += M1[a]*wv_[a];
        for (int b2=0;b2<3;++b2) wMw += wv_[a]*M2[a][b2]*wv_[b2];
      }
      const double NM = 1048576.0;
      double mean = Mw/NM + bj;
      double Ey2  = wMw/NM + 2.0*bj*Mw/NM + bj*bj;
      double var  = Ey2 - mean*mean;
      double scale = gj / sqrt(var + 1e-5);
      afold_g[t]      = (float)(wv_[0]*scale);
      afold_g[64+t]   = (float)(wv_[1]*scale);
      afold_g[128+t]  = (float)(wv_[2]*scale);
      scfold_g[t]     = (float)(bj*scale + bej - mean*scale);
    }
  }
}

// ========== KPB: pbias table, 512 blocks x 256 thr, 8 queries/block ==========
// Hoists the 64-iter MLP out of k9 (it was ~40% of k9's VALU work, executed
// inside a barrier-heavy kernel). Barrier-free main loop at full-chip spread.
// Layout: pbias_b[(b*256+s)*8 + qi] for queries n = b*8+qi. Identical fp32
// accumulation order to the in-k9 version.
__global__ __launch_bounds__(256) void kpb(const float* A, const int* idx,
    const float* afold_g, const float* scfold_g, float* pbias_b)
{
  __shared__ float saf[3][64];
  __shared__ float ssc[64];
  __shared__ float w2s[64];
  __shared__ __align__(16) float e4q[64][8];
  __shared__ float xs[8], ys[8], zs[8];
  int t = threadIdx.x, b = blockIdx.x;
  if (t < 64){
    saf[0][t] = afold_g[t]; saf[1][t] = afold_g[64+t]; saf[2][t] = afold_g[128+t];
    ssc[t] = scfold_g[t]; w2s[t] = A[OF_PW2+t];
  } else if (t < 72){
    int qi = t - 64;
    int4 q = ((const int4*)idx)[b*8 + qi];
    xs[qi] = (float)q.y; ys[qi] = (float)q.z; zs[qi] = (float)q.w;
  }
  __syncthreads();
  for (int e = t; e < 512; e += 256){
    int j = e & 63, qi = e >> 6;
    e4q[j][qi] = saf[0][j]*xs[qi] + saf[1][j]*ys[qi] + saf[2][j]*zs[qi];
  }
  __syncthreads();
  int4 q0 = ((const int4*)idx)[t*16];
  float ux = (float)(q0.y>>2), uy = (float)(q0.z>>2), uz = (float)(q0.w>>2);
  float pb2 = A[OF_PB2];
  float pbv[8];
  #pragma unroll
  for (int i=0;i<8;++i) pbv[i] = pb2;
  #pragma unroll 2
  for (int j=0;j<64;++j){
    float dj = ssc[j] - (saf[0][j]*ux + saf[1][j]*uy + saf[2][j]*uz);
    float wj = w2s[j];
    float4 e0 = *(const float4*)&e4q[j][0];
    float4 e1 = *(const float4*)&e4q[j][4];
    pbv[0] += fmaxf(e0.x+dj,0.f)*wj; pbv[1] += fmaxf(e0.y+dj,0.f)*wj;
    pbv[2] += fmaxf(e0.z+dj,0.f)*wj; pbv[3] += fmaxf(e0.w+dj,0.f)*wj;
    pbv[4] += fmaxf(e1.x+dj,0.f)*wj; pbv[5] += fmaxf(e1.y+dj,0.f)*wj;
    pbv[6] += fmaxf(e1.z+dj,0.f)*wj; pbv[7] += fmaxf(e1.w+dj,0.f)*wj;
  }
  float* dst = pbias_b + ((size_t)b*256 + t)*8;
  *(float4*)dst       = make_float4(pbv[0],pbv[1],pbv[2],pbv[3]);
  *(float4*)(dst + 4) = make_float4(pbv[4],pbv[5],pbv[6],pbv[7]);
}

// ========== K6: 512 blocks (role = b>>8: 0=k, 1=v); map scatter on role 0 ==========
__global__ __launch_bounds__(256) void k6_fused(const float* t1T, const float* A,
    const int* idx, int* map, float* kb, float* vb){
  __shared__ float row[CD];
  __shared__ float cpar[2][CD];
  __shared__ float hrow[CD];
  int t = threadIdx.x;
  int role = blockIdx.x >> 8, s = blockIdx.x & 255;
  if (role == 0 && t >= 128 && t < 144){
    int v = s*16 + (t-128);
    int4 q = ((const int4*)idx)[v];
    map[((q.x*XD + q.y)*YD + q.z)*ZD + q.w] = v;
  }
  if (t < CD){
    const float4* col = (const float4*)(t1T + (size_t)t*NSV);
    float sum=0.f, sq=0.f;
    #pragma unroll 8
    for (int i=0;i<NSV/4;++i){
      float4 v = col[i];
      sum += v.x+v.y+v.z+v.w;
      sq  += v.x*v.x+v.y*v.y+v.z*v.z+v.w*v.w;
    }
    float mean = sum*(1.f/256.f);
    float var  = sq*(1.f/256.f) - mean*mean;
    float scv = A[OF_CG1+t]*rsqrtf(var+EPSF);
    float shv = A[OF_CBE1+t] - mean*scv;
    row[t] = fmaxf(t1T[(size_t)t*NSV + s]*scv + shv, 0.f);
  }
  __syncthreads();
  int c = t&127, half = t>>7;
  {
    const float* W = A + OF_CW2;
    float acc = 0.f;
    #pragma unroll 8
    for (int i=half*64;i<half*64+64;++i) acc += row[i]*W[i*CD+c];
    cpar[half][c] = acc;
  }
  __syncthreads();
  if (t < CD) hrow[t] = cpar[0][t]+cpar[1][t]+A[OF_CB2+t];
  __syncthreads();
  // proj: split K over thread halves
  {
    const float* W = role ? (A+OF_WV) : (A+OF_WK);
    float acc = 0.f;
    #pragma unroll 8
    for (int i=half*64;i<half*64+64;++i) acc += hrow[i]*W[i*CD+c];
    cpar[half][c] = acc;
  }
  __syncthreads();
  if (t < CD){
    float v = cpar[0][t]+cpar[1][t] + (role ? A[OF_BV+t] : A[OF_BK+t]);
    if (role) vb[(size_t)s*CD+t] = v; else kb[(size_t)s*CD+t] = v;
  }
}

// ========== K9 v5: Round-2 structure (Q=4, 256 thr) minus the pbias MLP ==========
// VALUBusy saturates ~40% across 36/45/66% occupancy -> issue-structure-bound,
// so cut instructions instead of adding waves. pbias externalized to kpb
// (~40% of per-thread VALU removed + one barrier phase). Dataflow otherwise
// identical to the proven Round-2 kernel.
#define CGRP(row,hh) (((hh) + ((row)>>1)) & 3)

__global__ __launch_bounds__(256, 6) void k9_attn(
    const float* A, const int* idx, const float* pbias_b,
    const float* kb, const float* vb, const float* qb, float* yb)
{
  __shared__ __align__(16) float q4s[4][CD];       // 2 KB
  __shared__ __align__(16) float scf[NSV][16];     // 16 KB swizzled probs, 4 heads
  __shared__ __align__(16) float ctxT[CD*4];       // 2 KB
  __shared__ float cpart[4][4][64];                // 4 KB
  __shared__ float rinv[32];
  int t = threadIdx.x;
  int n0 = blockIdx.x*4;
  if (t < 128) ((float4*)q4s)[t] = ((const float4*)(qb + (size_t)n0*CD))[t];
  // ---- pbias for supervoxel s = t: one aligned float4 from the kpb table
  float4 pbq = *(const float4*)(pbias_b + ((size_t)(n0>>3)*256 + t)*8 + (n0&7));
  float pbv[4] = {pbq.x, pbq.y, pbq.z, pbq.w};
  __syncthreads();
  const float4* krow = (const float4*)(kb + (size_t)t*CD);
  #pragma unroll
  for (int p=0;p<2;++p){
    // ---- scores + exp for heads h = 4p..4p+3, supervoxel s = t
    {
      #pragma unroll
      for (int hh=0; hh<4; ++hh){
        int h = p*4 + hh;
        float4 k0 = krow[h*4+0], k1 = krow[h*4+1], k2 = krow[h*4+2], k3 = krow[h*4+3];
        float pr[4];
        #pragma unroll
        for (int g=0; g<4; ++g){
          const float* qg = &q4s[g][h*DHD];
          float dot = qg[0]*k0.x + qg[1]*k0.y + qg[2]*k0.z + qg[3]*k0.w
                    + qg[4]*k1.x + qg[5]*k1.y + qg[6]*k1.z + qg[7]*k1.w
                    + qg[8]*k2.x + qg[9]*k2.y + qg[10]*k2.z + qg[11]*k2.w
                    + qg[12]*k3.x + qg[13]*k3.y + qg[14]*k3.z + qg[15]*k3.w;
          pr[g] = __expf(dot*0.25f + pbv[g]);
        }
        *(float4*)&scf[t][CGRP(t,hh)*4] = make_float4(pr[0],pr[1],pr[2],pr[3]);
      }
    }
    __syncthreads();
    // ---- denominators for these 4 heads: wave g handles query g
    {
      int g = t>>6, lane = t&63;
      #pragma unroll
      for (int hh=0; hh<4; ++hh){
        float s0 = 0.f;
        #pragma unroll
        for (int k=0;k<4;++k){
          int r = lane + 64*k;
          s0 += scf[r][CGRP(r,hh)*4 + g];
        }
        #pragma unroll
        for (int o=32;o;o>>=1) s0 += __shfl_xor(s0,o,64);
        if (lane==0) rinv[g*8 + p*4 + hh] = 1.f/s0;
      }
    }
    // ---- PV for channels [64p, 64p+64): thread = (quarter q : 4, channel c : 64)
    {
      int q = t>>6, c = t&63;
      int hh = c>>4;
      const float* vcol = vb + p*64 + c;
      float a0=0.f, a1=0.f, a2=0.f, a3=0.f;
      #pragma unroll 4
      for (int s=q*64; s<q*64+64; ++s){
        float v = vcol[(size_t)s*CD];
        float4 pv = *(const float4*)&scf[s][CGRP(s,hh)*4];
        a0 += pv.x*v; a1 += pv.y*v; a2 += pv.z*v; a3 += pv.w*v;
      }
      cpart[q][0][c]=a0; cpart[q][1][c]=a1; cpart[q][2][c]=a2; cpart[q][3][c]=a3;
    }
    __syncthreads();
    // ---- assemble ctxT for these channels (rinv ready: written before the barrier)
    {
      int gsel = t>>6, c = t&63;
      int ch = p*64 + c, h = ch>>4;
      ctxT[ch*4+gsel] = (cpart[0][gsel][c]+cpart[1][gsel][c]
                        +cpart[2][gsel][c]+cpart[3][gsel][c]) * rinv[gsel*8+h];
    }
    // no barrier needed here: next pass's scf writes are safe (all scf reads of
    // this pass completed before the post-PV barrier), cpart/rinv overwrites in
    // the next pass happen only after its own post-score barrier.
  }
  __syncthreads();
  // ---- wo
  {
    int half=t>>7, c=t&127;
    const float* wo = A + OF_WO;
    float acc[4]={0.f,0.f,0.f,0.f};
    #pragma unroll 4
    for (int i=half*64;i<half*64+64;++i){
      float wv = wo[i*CD+c];
      float4 r = *(const float4*)&ctxT[i*4];
      acc[0]+=r.x*wv; acc[1]+=r.y*wv; acc[2]+=r.z*wv; acc[3]+=r.w*wv;
    }
    // slot = (channel-half chi)*2 + (K-half): reader sums the two K-halves
    #pragma unroll
    for (int g=0;g<4;++g) cpart[(c>>6)*2 + half][g][c&63] = acc[g];
  }
  __syncthreads();
  if (t < CD){
    float bov = A[OF_BO+t];
    int chi = t>>6, cl = t&63;
    #pragma unroll
    for (int g=0;g<4;++g)
      ctxT[t*4+g] = cpart[chi*2+0][g][cl] + cpart[chi*2+1][g][cl] + bov
                  + A[OF_FEAT + (size_t)(n0+g)*CD + t];
  }
  __syncthreads();
  // ---- LayerNorm: wave g handles row g
  {
    int g = t>>6, lane = t&63;
    float x0 = ctxT[lane*4+g], x1 = ctxT[(lane+64)*4+g];
    float s1 = x0+x1, s2 = x0*x0+x1*x1;
    #pragma unroll
    for (int o=32;o;o>>=1){ s1 += __shfl_xor(s1,o,64); s2 += __shfl_xor(s2,o,64); }
    float mean = s1*(1.f/128.f);
    float var  = s2*(1.f/128.f) - mean*mean;
    float rs = rsqrtf(var + EPSF);
    yb[(size_t)(n0+g)*CD + lane]    = (x0-mean)*rs*A[OF_LNG+lane]    + A[OF_LNB+lane];
    yb[(size_t)(n0+g)*CD + lane+64] = (x1-mean)*rs*A[OF_LNG+lane+64] + A[OF_LNB+lane+64];
  }
}

// ========== K10: SubMConv3d, 8 voxels/block (512 blocks), weights hoisted ==========
__global__ __launch_bounds__(256) void k10_conv(const int* idx, const int* map,
    const float* yb, const float* A, const float* wt, const int* flag, void* outv)
{
  __shared__ int sco4[8][4];
  __shared__ int jn[8][27];
  __shared__ float partial[4][8][NCD];
  int t = threadIdx.x;
  int p0 = blockIdx.x*8;
  if (t < 32) ((int*)sco4)[t] = idx[4*p0 + t];
  __syncthreads();
  if (t < 216){
    int v = t/27, nb = t - v*27;
    int kd = nb/9, kh = (nb/3)%3, kw = nb%3;
    int bb = sco4[v][0];
    int nx = sco4[v][1]+kd-1, ny = sco4[v][2]+kh-1, nz = sco4[v][3]+kw-1;
    int j = -1;
    if ((unsigned)nx < XD && (unsigned)ny < YD && (unsigned)nz < ZD)
      j = map[((bb*XD+nx)*YD+ny)*ZD+nz];
    jn[v][nb] = j;
  }
  __syncthreads();
  int w = t>>6, l = t&63;
  int og = l & 3, cg = l >> 2;
  int c0 = cg*8;
  float acc[8][5];
  #pragma unroll
  for (int v=0;v<8;++v)
    #pragma unroll
    for (int oo=0;oo<5;++oo) acc[v][oo]=0.f;
  for (int nb = w; nb < 27; nb += 4){
    const float* wbase = wt + (size_t)nb*NCD*CD + c0;
    float4 wreg[10];
    #pragma unroll
    for (int oo=0;oo<5;++oo){
      wreg[oo*2]   = *(const float4*)(wbase + (size_t)(og*5+oo)*CD);
      wreg[oo*2+1] = *(const float4*)(wbase + (size_t)(og*5+oo)*CD + 4);
    }
    #pragma unroll
    for (int v=0; v<8; ++v){
      int j = jn[v][nb];
      if (j < 0) continue;
      const float4* y4 = (const float4*)(yb + (size_t)j*CD + c0);
      float4 ya = y4[0], ybb = y4[1];
      #pragma unroll
      for (int oo=0;oo<5;++oo){
        float4 wa = wreg[oo*2], wb = wreg[oo*2+1];
        acc[v][oo] += ya.x*wa.x + ya.y*wa.y + ya.z*wa.z + ya.w*wa.w
                    + ybb.x*wb.x + ybb.y*wb.y + ybb.z*wb.z + ybb.w*wb.w;
      }
    }
  }
  #pragma unroll
  for (int v=0;v<8;++v)
    #pragma unroll
    for (int oo=0;oo<5;++oo){
      float s = acc[v][oo];
      s += __shfl_xor(s, 4, 64);
      s += __shfl_xor(s, 8, 64);
      s += __shfl_xor(s, 16, 64);
      s += __shfl_xor(s, 32, 64);
      if (cg == 0) partial[w][v][og*5+oo] = s;
    }
  __syncthreads();
  if (t < 160){
    int v = t/20, o = t - v*20;
    float s = partial[0][v][o]+partial[1][v][o]+partial[2][v][o]+partial[3][v][o]
            + A[OF_SEGB+o];
    if (*flag) ((ushort_t*)outv)[(size_t)(p0+v)*NCD + o] = f2bf(s);
    else       ((float*)outv)[(size_t)(p0+v)*NCD + o]   = s;
  }
}

// ---------------- launch ----------------
extern "C" void kernel_launch(void* const* d_in, const int* in_sizes, int n_in,
                              void* d_out, int out_size, void* d_ws, size_t ws_size,
                              hipStream_t stream) {
  const int* idx = (const int*)d_in[0];

  char* w = (char*)d_ws;
  size_t off = 0;
  #define ALLOC(name, type, count) \
    type* name = (type*)(w + off); off += (((size_t)(count)*sizeof(type)) + 255) & ~(size_t)255;
  ALLOC(flag,   int,   64)
  ALLOC(arena,  float, ARENA_N)
  ALLOC(wt,     float, 27*NCD*CD)
  ALLOC(map,    int,   MAPN)
  ALLOC(afold,  float, 192)
  ALLOC(scfold, float, 64)
  ALLOC(t1T,    float, CD*NSV)
  ALLOC(kb,     float, NSV*CD)
  ALLOC(vbuf,   float, NSV*CD)
  ALLOC(qb,     float, NVOX*CD)
  ALLOC(yb,     float, NVOX*CD)
  ALLOC(pbias_b,float, 512*256*8)
  #undef ALLOC
  (void)off; (void)ws_size; (void)n_in; (void)in_sizes; (void)out_size;

  SrcPtrs sp;
  for (int i=0;i<25;++i) sp.p[i] = d_in[i+1];

  kprep   <<<512, 512, 0, stream>>>(sp, idx, flag, arena, wt, map, afold, scfold, qb, t1T);
  kpb     <<<512, 256, 0, stream>>>(arena, idx, afold, scfold, pbias_b);
  k6_fused<<<NSV*2, 256, 0, stream>>>(t1T, arena, idx, map, kb, vbuf);
  k9_attn <<<NVOX/4, 256, 0, stream>>>(arena, idx, pbias_b, kb, vbuf, qb, yb);
  k10_conv<<<NVOX/8, 256, 0, stream>>>(idx, map, yb, arena, wt, flag, d_out);
}

// Round 6
// 200.700 us; speedup vs baseline: 1.0382x; 1.0382x over previous
//
#include <hip/hip_runtime.h>

typedef unsigned short ushort_t;

#define NVOX 4096
#define NSV  256
#define XD   128
#define YD   128
#define ZD   16
#define CD   128
#define NCD  20
#define HD   8
#define DHD  16
#define MAPN 524288
#define EPSF 1e-5f

// ---- fp32 arena offsets (floats) ----
#define OF_FEAT 0
#define OF_CW1  524288
#define OF_CB1  540672
#define OF_CG1  540800
#define OF_CBE1 540928
#define OF_CW2  541056
#define OF_CB2  557440
#define OF_PW1  557568
#define OF_PB1  557760
#define OF_PG1  557824
#define OF_PBE1 557888
#define OF_PW2  557952
#define OF_PB2  558016
#define OF_WQ   558080
#define OF_BQ   574464
#define OF_WK   574592
#define OF_BK   590976
#define OF_WV   591104
#define OF_BV   607488
#define OF_WO   607616
#define OF_BO   624000
#define OF_LNG  624128
#define OF_LNB  624256
#define OF_SEGW 624384
#define OF_SEGB 693504
#define ARENA_N 693568
#define TOTCVT2 100053   /* arena convert, FEAT excluded (k9 reads source) */

__device__ __forceinline__ float bf2f(const ushort_t* p){
  return __uint_as_float(((unsigned)(*p)) << 16);
}
__device__ __forceinline__ ushort_t f2bf(float f){
  unsigned u = __float_as_uint(f);
  u += 0x7fffu + ((u >> 16) & 1u);
  return (ushort_t)(u >> 16);
}
__device__ __forceinline__ float unlo(unsigned u){ return __uint_as_float(u << 16); }
__device__ __forceinline__ float unhi(unsigned u){ return __uint_as_float(u & 0xffff0000u); }

struct SrcPtrs { const void* p[25]; };

// segments 1..24 of the original table (FEAT dropped); src = sp.p[s+1]
__device__ const int g_cnt2[24] = {16384,128,128,128,16384,128,192,64,64,64,64,1,
                                   16384,128,16384,128,16384,128,16384,128,128,128,0,20};
__device__ const int g_off2[24] = {OF_CW1,OF_CB1,OF_CG1,OF_CBE1,OF_CW2,OF_CB2,
                                   OF_PW1,OF_PB1,OF_PG1,OF_PBE1,OF_PW2,OF_PB2,
                                   OF_WQ,OF_BQ,OF_WK,OF_BK,OF_WV,OF_BV,OF_WO,OF_BO,
                                   OF_LNG,OF_LNB,OF_SEGW,OF_SEGB};

__device__ __forceinline__ float ldi(const void* p, int off, int fl){
  return fl ? bf2f((const ushort_t*)p + off) : ((const float*)p)[off];
}

struct SPREP {
  float frows[16][CD];     // 8 KB
  float qpart[2][16][CD];  // 16 KB
  float part[8][CD];       // 4 KB
  float cfs[CD];           // 0.5 KB
  float gpart[8][CD];      // 4 KB
};
union __align__(16) UPREP { SPREP sv; int smom[18]; };

// ========== KPREP (512 threads) ==========
__global__ __launch_bounds__(512) void kprep(SrcPtrs sp, const int* idx, int* flag,
    float* arena, float* wt, int* map, float* afold_g, float* scfold_g,
    float* qb, float* t1T)
{
  __shared__ UPREP sm;
  __shared__ int sm_flag;
  int t = threadIdx.x, b = blockIdx.x;
  if (t < 64){
    const ushort_t* f16 = (const ushort_t*)sp.p[0];
    unsigned u = f16[2*t];
    int e = (u >> 7) & 0xFF;
    int sane = (u == 0 || (e >= 90 && e <= 150)) ? 1 : 0;
    unsigned long long bl = __ballot(sane);
    if (t == 0) sm_flag = (__popcll(bl) >= 48) ? 1 : 0;
  }
  __syncthreads();
  const int fl = sm_flag;

  if (b < 255){
    int gid = b*512 + t;
    const int GS = 255*512;
    if (gid == 0) *flag = fl;
    for (int k=gid; k<MAPN; k+=GS) map[k] = -1;
    for (int el=gid; el<TOTCVT2; el+=GS){
      int s=0, rem=el;
      while (rem >= g_cnt2[s]){ rem -= g_cnt2[s]; ++s; }
      arena[g_off2[s]+rem] = ldi(sp.p[s+1], rem, fl);
    }
    for (int k=gid; k<27*NCD*CD; k+=GS){
      int nb = k/(NCD*CD); int rem = k - nb*(NCD*CD); int o = rem/CD, i = rem - o*CD;
      wt[k] = ldi(sp.p[23], nb*(CD*NCD) + i*NCD + o, fl);
    }
  } else if (b < 511){
    int sv = b - 255;
    int rb = sv*16;
    if (fl){
      const uint2* fsrc = (const uint2*)((const ushort_t*)sp.p[0] + (size_t)rb*CD);
      uint2 u = fsrc[t];
      float* dst = &sm.sv.frows[t>>5][(t&31)*4];
      dst[0]=unlo(u.x); dst[1]=unhi(u.x); dst[2]=unlo(u.y); dst[3]=unhi(u.y);
    } else {
      const float4* fsrc = (const float4*)((const float*)sp.p[0] + (size_t)rb*CD);
      ((float4*)sm.sv.frows)[t] = fsrc[t];
    }
    __syncthreads();
    // ---- q-proj: thread = (c8:16, row:16, khalf:2)
    {
      int c8 = (t&15)*8, r = (t>>4)&15, kh = t>>8;
      int i0 = kh*64;
      float acc[8] = {0.f,0.f,0.f,0.f,0.f,0.f,0.f,0.f};
      if (fl){
        const ushort_t* wqp = (const ushort_t*)sp.p[13];
        #pragma unroll 4
        for (int i=i0; i<i0+64; ++i){
          uint4 w4 = *(const uint4*)(wqp + (size_t)i*CD + c8);
          float fr = sm.sv.frows[r][i];
          acc[0] += unlo(w4.x)*fr; acc[1] += unhi(w4.x)*fr;
          acc[2] += unlo(w4.y)*fr; acc[3] += unhi(w4.y)*fr;
          acc[4] += unlo(w4.z)*fr; acc[5] += unhi(w4.z)*fr;
          acc[6] += unlo(w4.w)*fr; acc[7] += unhi(w4.w)*fr;
        }
      } else {
        const float* wqp = (const float*)sp.p[13];
        #pragma unroll 4
        for (int i=i0; i<i0+64; ++i){
          float4 wa = *(const float4*)(wqp + (size_t)i*CD + c8);
          float4 wb = *(const float4*)(wqp + (size_t)i*CD + c8 + 4);
          float fr = sm.sv.frows[r][i];
          acc[0]+=wa.x*fr; acc[1]+=wa.y*fr; acc[2]+=wa.z*fr; acc[3]+=wa.w*fr;
          acc[4]+=wb.x*fr; acc[5]+=wb.y*fr; acc[6]+=wb.z*fr; acc[7]+=wb.w*fr;
        }
      }
      #pragma unroll
      for (int j=0;j<8;++j) sm.sv.qpart[kh][r][c8+j] = acc[j];
    }
    __syncthreads();
    for (int e = t; e < 16*CD; e += 512){
      int r = e>>7, c = e&127;
      qb[(size_t)(rb+r)*CD + c] = sm.sv.qpart[0][r][c] + sm.sv.qpart[1][r][c]
                                + ldi(sp.p[14], c, fl);
    }
    // ---- segment softmax-sum: 8 waves x 2 rows
    {
      int w = t>>6, l = t&63;
      float a0 = 0.f, a1 = 0.f;
      #pragma unroll
      for (int k=0;k<2;++k){
        int r = w*2 + k;
        float f0 = sm.sv.frows[r][l];
        float f1 = sm.sv.frows[r][l+64];
        float m = fmaxf(f0,f1);
        #pragma unroll
        for (int o=32;o;o>>=1) m = fmaxf(m, __shfl_xor(m,o,64));
        float e0 = __expf(f0-m), e1 = __expf(f1-m);
        float ssum = e0+e1;
        #pragma unroll
        for (int o=32;o;o>>=1) ssum += __shfl_xor(ssum,o,64);
        float inv = 1.f/ssum;
        a0 += e0*inv; a1 += e1*inv;
      }
      sm.sv.part[w][l] = a0; sm.sv.part[w][l+64] = a1;
    }
    __syncthreads();
    if (t < CD){
      float s = 0.f;
      #pragma unroll
      for (int w=0;w<8;++w) s += sm.sv.part[w][t];
      sm.sv.cfs[t] = s;
    }
    __syncthreads();
    // ---- GEMV1: thread = (c2:64, kg:8)
    {
      int c2 = (t&63)*2, kg = t>>6;
      int i0 = kg*16;
      float a0 = 0.f, a1 = 0.f;
      if (fl){
        const ushort_t* W = (const ushort_t*)sp.p[1];
        #pragma unroll 4
        for (int i=i0; i<i0+16; ++i){
          unsigned w = *(const unsigned*)(W + (size_t)i*CD + c2);
          float cfv = sm.sv.cfs[i];
          a0 += unlo(w)*cfv; a1 += unhi(w)*cfv;
        }
      } else {
        const float* W = (const float*)sp.p[1];
        #pragma unroll 4
        for (int i=i0; i<i0+16; ++i){
          float2 w = *(const float2*)(W + (size_t)i*CD + c2);
          float cfv = sm.sv.cfs[i];
          a0 += w.x*cfv; a1 += w.y*cfv;
        }
      }
      sm.sv.gpart[kg][c2] = a0; sm.sv.gpart[kg][c2+1] = a1;
    }
    __syncthreads();
    if (t < CD){
      float s = 0.f;
      #pragma unroll
      for (int kg=0;kg<8;++kg) s += sm.sv.gpart[kg][t];
      t1T[(size_t)t*NSV + sv] = s + ldi(sp.p[2], t, fl);
    }
  } else {
    // ---- b == 511: moments + BN fold (wave-reduced, no per-lane LDS atomic storms)
    if (t < 18) sm.smom[t] = 0;
    __syncthreads();
    {
      // voxel moments
      int sacc[9] = {0,0,0,0,0,0,0,0,0};
      for (int v = t; v < NVOX; v += 512){
        int4 q = ((const int4*)idx)[v];
        sacc[0]+=q.y; sacc[1]+=q.z; sacc[2]+=q.w;
        sacc[3]+=q.y*q.y; sacc[4]+=q.z*q.z; sacc[5]+=q.w*q.w;
        sacc[6]+=q.y*q.z; sacc[7]+=q.y*q.w; sacc[8]+=q.z*q.w;
      }
      // supervoxel (cell) moments
      int um[9] = {0,0,0,0,0,0,0,0,0};
      if (t < 256){
        int4 q = ((const int4*)idx)[t*16];
        int gx=q.y>>2, gy=q.z>>2, gz=q.w>>2;
        um[0]=gx; um[1]=gy; um[2]=gz;
        um[3]=gx*gx; um[4]=gy*gy; um[5]=gz*gz;
        um[6]=gx*gy; um[7]=gx*gz; um[8]=gy*gz;
      }
      // 64-lane shuffle tree per moment, one atomic per wave per moment
      int lane = t & 63;
      #pragma unroll
      for (int i=0;i<9;++i){
        int s = sacc[i];
        int u = um[i];
        #pragma unroll
        for (int o=32;o;o>>=1){
          s += __shfl_xor(s, o, 64);
          u += __shfl_xor(u, o, 64);
        }
        if (lane == 0){
          if (s) atomicAdd(&sm.smom[9+i], s);
          if (u) atomicAdd(&sm.smom[i], u);
        }
      }
    }
    __syncthreads();
    if (t < 64){
      int* smom = sm.smom;
      double U1[3]={(double)smom[0],(double)smom[1],(double)smom[2]};
      double S1[3]={(double)smom[9],(double)smom[10],(double)smom[11]};
      double Uxx[3][3], Sxx[3][3];
      Uxx[0][0]=smom[3]; Uxx[1][1]=smom[4]; Uxx[2][2]=smom[5];
      Uxx[0][1]=Uxx[1][0]=smom[6]; Uxx[0][2]=Uxx[2][0]=smom[7]; Uxx[1][2]=Uxx[2][1]=smom[8];
      Sxx[0][0]=smom[12]; Sxx[1][1]=smom[13]; Sxx[2][2]=smom[14];
      Sxx[0][1]=Sxx[1][0]=smom[15]; Sxx[0][2]=Sxx[2][0]=smom[16]; Sxx[1][2]=Sxx[2][1]=smom[17];
      double M1[3], M2[3][3];
      for (int a=0;a<3;++a) M1[a] = 256.0*S1[a] - 4096.0*U1[a];
      for (int a=0;a<3;++a)
        for (int b2=0;b2<3;++b2)
          M2[a][b2] = 256.0*Sxx[a][b2] - S1[a]*U1[b2] - S1[b2]*U1[a] + 4096.0*Uxx[a][b2];
      double wv_[3]={(double)ldi(sp.p[7],t,fl),(double)ldi(sp.p[7],64+t,fl),(double)ldi(sp.p[7],128+t,fl)};
      double bj=(double)ldi(sp.p[8],t,fl), gj=(double)ldi(sp.p[9],t,fl), bej=(double)ldi(sp.p[10],t,fl);
      double Mw=0.0, wMw=0.0;
      for (int a=0;a<3;++a){
        Mw += M1[a]*wv_[a];
        for (int b2=0;b2<3;++b2) wMw += wv_[a]*M2[a][b2]*wv_[b2];
      }
      const double NM = 1048576.0;
      double mean = Mw/NM + bj;
      double Ey2  = wMw/NM + 2.0*bj*Mw/NM + bj*bj;
      double var  = Ey2 - mean*mean;
      double scale = gj / sqrt(var + 1e-5);
      afold_g[t]      = (float)(wv_[0]*scale);
      afold_g[64+t]   = (float)(wv_[1]*scale);
      afold_g[128+t]  = (float)(wv_[2]*scale);
      scfold_g[t]     = (float)(bj*scale + bej - mean*scale);
    }
  }
}

// ========== K6PB: 1024 blocks. b<512: pbias table (8 queries/block).
//            b in [512,1024): k6 GEMVs (role = (b-512)>>8: 0=k, 1=v). ==========
__global__ __launch_bounds__(256) void k6pb(const float* t1T, const float* A,
    const int* idx, int* map, float* kb, float* vb,
    const float* afold_g, const float* scfold_g, float* pbias_b)
{
  __shared__ float saf[3][64];
  __shared__ float ssc[64];
  __shared__ float w2s[64];
  __shared__ __align__(16) float e4q[64][8];
  __shared__ float xs[8], ys[8], zs[8];
  __shared__ float row[CD];
  __shared__ float cpar[2][CD];
  __shared__ float hrow[CD];
  int t = threadIdx.x, b = blockIdx.x;
  if (b < 512){
    // ---- pbias: hoisted 64-iter MLP; layout pbias_b[(b*256+s)*8 + qi]
    if (t < 64){
      saf[0][t] = afold_g[t]; saf[1][t] = afold_g[64+t]; saf[2][t] = afold_g[128+t];
      ssc[t] = scfold_g[t]; w2s[t] = A[OF_PW2+t];
    } else if (t < 72){
      int qi = t - 64;
      int4 q = ((const int4*)idx)[b*8 + qi];
      xs[qi] = (float)q.y; ys[qi] = (float)q.z; zs[qi] = (float)q.w;
    }
    __syncthreads();
    for (int e = t; e < 512; e += 256){
      int j = e & 63, qi = e >> 6;
      e4q[j][qi] = saf[0][j]*xs[qi] + saf[1][j]*ys[qi] + saf[2][j]*zs[qi];
    }
    __syncthreads();
    int4 q0 = ((const int4*)idx)[t*16];
    float ux = (float)(q0.y>>2), uy = (float)(q0.z>>2), uz = (float)(q0.w>>2);
    float pb2 = A[OF_PB2];
    float pbv[8];
    #pragma unroll
    for (int i=0;i<8;++i) pbv[i] = pb2;
    #pragma unroll 2
    for (int j=0;j<64;++j){
      float dj = ssc[j] - (saf[0][j]*ux + saf[1][j]*uy + saf[2][j]*uz);
      float wj = w2s[j];
      float4 e0 = *(const float4*)&e4q[j][0];
      float4 e1 = *(const float4*)&e4q[j][4];
      pbv[0] += fmaxf(e0.x+dj,0.f)*wj; pbv[1] += fmaxf(e0.y+dj,0.f)*wj;
      pbv[2] += fmaxf(e0.z+dj,0.f)*wj; pbv[3] += fmaxf(e0.w+dj,0.f)*wj;
      pbv[4] += fmaxf(e1.x+dj,0.f)*wj; pbv[5] += fmaxf(e1.y+dj,0.f)*wj;
      pbv[6] += fmaxf(e1.z+dj,0.f)*wj; pbv[7] += fmaxf(e1.w+dj,0.f)*wj;
    }
    float* dst = pbias_b + ((size_t)b*256 + t)*8;
    *(float4*)dst       = make_float4(pbv[0],pbv[1],pbv[2],pbv[3]);
    *(float4*)(dst + 4) = make_float4(pbv[4],pbv[5],pbv[6],pbv[7]);
    return;
  }
  // ---- k6: BN-fold + relu + cw2 + {wk|wv} projection for supervoxel s
  int role = (b - 512) >> 8, s = (b - 512) & 255;
  if (role == 0 && t >= 128 && t < 144){
    int v = s*16 + (t-128);
    int4 q = ((const int4*)idx)[v];
    map[((q.x*XD + q.y)*YD + q.z)*ZD + q.w] = v;
  }
  if (t < CD){
    const float4* col = (const float4*)(t1T + (size_t)t*NSV);
    float sum=0.f, sq=0.f;
    #pragma unroll 8
    for (int i=0;i<NSV/4;++i){
      float4 v = col[i];
      sum += v.x+v.y+v.z+v.w;
      sq  += v.x*v.x+v.y*v.y+v.z*v.z+v.w*v.w;
    }
    float mean = sum*(1.f/256.f);
    float var  = sq*(1.f/256.f) - mean*mean;
    float scv = A[OF_CG1+t]*rsqrtf(var+EPSF);
    float shv = A[OF_CBE1+t] - mean*scv;
    row[t] = fmaxf(t1T[(size_t)t*NSV + s]*scv + shv, 0.f);
  }
  __syncthreads();
  int c = t&127, half = t>>7;
  {
    const float* W = A + OF_CW2;
    float acc = 0.f;
    #pragma unroll 8
    for (int i=half*64;i<half*64+64;++i) acc += row[i]*W[i*CD+c];
    cpar[half][c] = acc;
  }
  __syncthreads();
  if (t < CD) hrow[t] = cpar[0][t]+cpar[1][t]+A[OF_CB2+t];
  __syncthreads();
  {
    const float* W = role ? (A+OF_WV) : (A+OF_WK);
    float acc = 0.f;
    #pragma unroll 8
    for (int i=half*64;i<half*64+64;++i) acc += hrow[i]*W[i*CD+c];
    cpar[half][c] = acc;
  }
  __syncthreads();
  if (t < CD){
    float v = cpar[0][t]+cpar[1][t] + (role ? A[OF_BV+t] : A[OF_BK+t]);
    if (role) vb[(size_t)s*CD+t] = v; else kb[(size_t)s*CD+t] = v;
  }
}

// ========== K9 v6: Q=4 structure; pbias external; residual reads source feat ==========
#define CGRP(row,hh) (((hh) + ((row)>>1)) & 3)

__global__ __launch_bounds__(256, 6) void k9_attn(
    const float* A, const int* idx, const float* pbias_b,
    const float* kb, const float* vb, const float* qb,
    const void* featsrc, const int* flag, float* yb)
{
  __shared__ __align__(16) float q4s[4][CD];       // 2 KB
  __shared__ __align__(16) float scf[NSV][16];     // 16 KB swizzled probs, 4 heads
  __shared__ __align__(16) float ctxT[CD*4];       // 2 KB
  __shared__ float cpart[4][4][64];                // 4 KB
  __shared__ float rinv[32];
  int t = threadIdx.x;
  int n0 = blockIdx.x*4;
  const int fl = *flag;
  if (t < 128) ((float4*)q4s)[t] = ((const float4*)(qb + (size_t)n0*CD))[t];
  // ---- pbias for supervoxel s = t: one aligned float4 from the k6pb table
  float4 pbq = *(const float4*)(pbias_b + ((size_t)(n0>>3)*256 + t)*8 + (n0&7));
  float pbv[4] = {pbq.x, pbq.y, pbq.z, pbq.w};
  __syncthreads();
  const float4* krow = (const float4*)(kb + (size_t)t*CD);
  #pragma unroll
  for (int p=0;p<2;++p){
    // ---- scores + exp for heads h = 4p..4p+3, supervoxel s = t
    {
      #pragma unroll
      for (int hh=0; hh<4; ++hh){
        int h = p*4 + hh;
        float4 k0 = krow[h*4+0], k1 = krow[h*4+1], k2 = krow[h*4+2], k3 = krow[h*4+3];
        float pr[4];
        #pragma unroll
        for (int g=0; g<4; ++g){
          const float4* qg4 = (const float4*)&q4s[g][h*DHD];
          float4 qa = qg4[0], qbv = qg4[1], qc = qg4[2], qd = qg4[3];
          float dot = qa.x*k0.x + qa.y*k0.y + qa.z*k0.z + qa.w*k0.w
                    + qbv.x*k1.x + qbv.y*k1.y + qbv.z*k1.z + qbv.w*k1.w
                    + qc.x*k2.x + qc.y*k2.y + qc.z*k2.z + qc.w*k2.w
                    + qd.x*k3.x + qd.y*k3.y + qd.z*k3.z + qd.w*k3.w;
          pr[g] = __expf(dot*0.25f + pbv[g]);
        }
        *(float4*)&scf[t][CGRP(t,hh)*4] = make_float4(pr[0],pr[1],pr[2],pr[3]);
      }
    }
    __syncthreads();
    // ---- denominators for these 4 heads: wave g handles query g
    {
      int g = t>>6, lane = t&63;
      #pragma unroll
      for (int hh=0; hh<4; ++hh){
        float s0 = 0.f;
        #pragma unroll
        for (int k=0;k<4;++k){
          int r = lane + 64*k;
          s0 += scf[r][CGRP(r,hh)*4 + g];
        }
        #pragma unroll
        for (int o=32;o;o>>=1) s0 += __shfl_xor(s0,o,64);
        if (lane==0) rinv[g*8 + p*4 + hh] = 1.f/s0;
      }
    }
    // ---- PV for channels [64p, 64p+64): thread = (quarter q : 4, channel c : 64)
    {
      int q = t>>6, c = t&63;
      int hh = c>>4;
      const float* vcol = vb + p*64 + c;
      float a0=0.f, a1=0.f, a2=0.f, a3=0.f;
      #pragma unroll 4
      for (int s=q*64; s<q*64+64; ++s){
        float v = vcol[(size_t)s*CD];
        float4 pv = *(const float4*)&scf[s][CGRP(s,hh)*4];
        a0 += pv.x*v; a1 += pv.y*v; a2 += pv.z*v; a3 += pv.w*v;
      }
      cpart[q][0][c]=a0; cpart[q][1][c]=a1; cpart[q][2][c]=a2; cpart[q][3][c]=a3;
    }
    __syncthreads();
    // ---- assemble ctxT for these channels (rinv ready: written before the barrier)
    {
      int gsel = t>>6, c = t&63;
      int ch = p*64 + c, h = ch>>4;
      ctxT[ch*4+gsel] = (cpart[0][gsel][c]+cpart[1][gsel][c]
                        +cpart[2][gsel][c]+cpart[3][gsel][c]) * rinv[gsel*8+h];
    }
    // no barrier needed here: next pass's scf writes are safe (all scf reads of
    // this pass completed before the post-PV barrier), cpart/rinv overwrites in
    // the next pass happen only after its own post-score barrier.
  }
  __syncthreads();
  // ---- wo
  {
    int half=t>>7, c=t&127;
    const float* wo = A + OF_WO;
    float acc[4]={0.f,0.f,0.f,0.f};
    #pragma unroll 4
    for (int i=half*64;i<half*64+64;++i){
      float wv = wo[i*CD+c];
      float4 r = *(const float4*)&ctxT[i*4];
      acc[0]+=r.x*wv; acc[1]+=r.y*wv; acc[2]+=r.z*wv; acc[3]+=r.w*wv;
    }
    // slot = (channel-half chi)*2 + (K-half): reader sums the two K-halves
    #pragma unroll
    for (int g=0;g<4;++g) cpart[(c>>6)*2 + half][g][c&63] = acc[g];
  }
  __syncthreads();
  if (t < CD){
    float bov = A[OF_BO+t];
    int chi = t>>6, cl = t&63;
    #pragma unroll
    for (int g=0;g<4;++g){
      float fv = fl ? bf2f((const ushort_t*)featsrc + (size_t)(n0+g)*CD + t)
                    : ((const float*)featsrc)[(size_t)(n0+g)*CD + t];
      ctxT[t*4+g] = cpart[chi*2+0][g][cl] + cpart[chi*2+1][g][cl] + bov + fv;
    }
  }
  __syncthreads();
  // ---- LayerNorm: wave g handles row g
  {
    int g = t>>6, lane = t&63;
    float x0 = ctxT[lane*4+g], x1 = ctxT[(lane+64)*4+g];
    float s1 = x0+x1, s2 = x0*x0+x1*x1;
    #pragma unroll
    for (int o=32;o;o>>=1){ s1 += __shfl_xor(s1,o,64); s2 += __shfl_xor(s2,o,64); }
    float mean = s1*(1.f/128.f);
    float var  = s2*(1.f/128.f) - mean*mean;
    float rs = rsqrtf(var + EPSF);
    yb[(size_t)(n0+g)*CD + lane]    = (x0-mean)*rs*A[OF_LNG+lane]    + A[OF_LNB+lane];
    yb[(size_t)(n0+g)*CD + lane+64] = (x1-mean)*rs*A[OF_LNG+lane+64] + A[OF_LNB+lane+64];
  }
}

// ========== K10: SubMConv3d, 8 voxels/block (512 blocks), weights hoisted ==========
__global__ __launch_bounds__(256) void k10_conv(const int* idx, const int* map,
    const float* yb, const float* A, const float* wt, const int* flag, void* outv)
{
  __shared__ int sco4[8][4];
  __shared__ int jn[8][27];
  __shared__ float partial[4][8][NCD];
  int t = threadIdx.x;
  int p0 = blockIdx.x*8;
  if (t < 32) ((int*)sco4)[t] = idx[4*p0 + t];
  __syncthreads();
  if (t < 216){
    int v = t/27, nb = t - v*27;
    int kd = nb/9, kh = (nb/3)%3, kw = nb%3;
    int bb = sco4[v][0];
    int nx = sco4[v][1]+kd-1, ny = sco4[v][2]+kh-1, nz = sco4[v][3]+kw-1;
    int j = -1;
    if ((unsigned)nx < XD && (unsigned)ny < YD && (unsigned)nz < ZD)
      j = map[((bb*XD+nx)*YD+ny)*ZD+nz];
    jn[v][nb] = j;
  }
  __syncthreads();
  int w = t>>6, l = t&63;
  int og = l & 3, cg = l >> 2;
  int c0 = cg*8;
  float acc[8][5];
  #pragma unroll
  for (int v=0;v<8;++v)
    #pragma unroll
    for (int oo=0;oo<5;++oo) acc[v][oo]=0.f;
  for (int nb = w; nb < 27; nb += 4){
    const float* wbase = wt + (size_t)nb*NCD*CD + c0;
    float4 wreg[10];
    #pragma unroll
    for (int oo=0;oo<5;++oo){
      wreg[oo*2]   = *(const float4*)(wbase + (size_t)(og*5+oo)*CD);
      wreg[oo*2+1] = *(const float4*)(wbase + (size_t)(og*5+oo)*CD + 4);
    }
    #pragma unroll
    for (int v=0; v<8; ++v){
      int j = jn[v][nb];
      if (j < 0) continue;
      const float4* y4 = (const float4*)(yb + (size_t)j*CD + c0);
      float4 ya = y4[0], ybb = y4[1];
      #pragma unroll
      for (int oo=0;oo<5;++oo){
        float4 wa = wreg[oo*2], wb = wreg[oo*2+1];
        acc[v][oo] += ya.x*wa.x + ya.y*wa.y + ya.z*wa.z + ya.w*wa.w
                    + ybb.x*wb.x + ybb.y*wb.y + ybb.z*wb.z + ybb.w*wb.w;
      }
    }
  }
  #pragma unroll
  for (int v=0;v<8;++v)
    #pragma unroll
    for (int oo=0;oo<5;++oo){
      float s = acc[v][oo];
      s += __shfl_xor(s, 4, 64);
      s += __shfl_xor(s, 8, 64);
      s += __shfl_xor(s, 16, 64);
      s += __shfl_xor(s, 32, 64);
      if (cg == 0) partial[w][v][og*5+oo] = s;
    }
  __syncthreads();
  if (t < 160){
    int v = t/20, o = t - v*20;
    float s = partial[0][v][o]+partial[1][v][o]+partial[2][v][o]+partial[3][v][o]
            + A[OF_SEGB+o];
    if (*flag) ((ushort_t*)outv)[(size_t)(p0+v)*NCD + o] = f2bf(s);
    else       ((float*)outv)[(size_t)(p0+v)*NCD + o]   = s;
  }
}

// ---------------- launch ----------------
extern "C" void kernel_launch(void* const* d_in, const int* in_sizes, int n_in,
                              void* d_out, int out_size, void* d_ws, size_t ws_size,
                              hipStream_t stream) {
  const int* idx = (const int*)d_in[0];

  char* w = (char*)d_ws;
  size_t off = 0;
  #define ALLOC(name, type, count) \
    type* name = (type*)(w + off); off += (((size_t)(count)*sizeof(type)) + 255) & ~(size_t)255;
  ALLOC(flag,   int,   64)
  ALLOC(arena,  float, ARENA_N)
  ALLOC(wt,     float, 27*NCD*CD)
  ALLOC(map,    int,   MAPN)
  ALLOC(afold,  float, 192)
  ALLOC(scfold, float, 64)
  ALLOC(t1T,    float, CD*NSV)
  ALLOC(kb,     float, NSV*CD)
  ALLOC(vbuf,   float, NSV*CD)
  ALLOC(qb,     float, NVOX*CD)
  ALLOC(yb,     float, NVOX*CD)
  ALLOC(pbias_b,float, 512*256*8)
  #undef ALLOC
  (void)off; (void)ws_size; (void)n_in; (void)in_sizes; (void)out_size;

  SrcPtrs sp;
  for (int i=0;i<25;++i) sp.p[i] = d_in[i+1];

  kprep   <<<512, 512, 0, stream>>>(sp, idx, flag, arena, wt, map, afold, scfold, qb, t1T);
  k6pb    <<<1024, 256, 0, stream>>>(t1T, arena, idx, map, kb, vbuf, afold, scfold, pbias_b);
  k9_attn <<<NVOX/4, 256, 0, stream>>>(arena, idx, pbias_b, kb, vbuf, qb, d_in[1], flag, yb);
  k10_conv<<<NVOX/8, 256, 0, stream>>>(idx, map, yb, arena, wt, flag, d_out);
}

// Round 7
// 197.446 us; speedup vs baseline: 1.0553x; 1.0165x over previous
//
#include <hip/hip_runtime.h>

typedef unsigned short ushort_t;

#define NVOX 4096
#define NSV  256
#define XD   128
#define YD   128
#define ZD   16
#define CD   128
#define NCD  20
#define HD   8
#define DHD  16
#define MAPN 524288
#define EPSF 1e-5f

// ---- fp32 arena offsets (floats) ----
#define OF_FEAT 0
#define OF_CW1  524288
#define OF_CB1  540672
#define OF_CG1  540800
#define OF_CBE1 540928
#define OF_CW2  541056
#define OF_CB2  557440
#define OF_PW1  557568
#define OF_PB1  557760
#define OF_PG1  557824
#define OF_PBE1 557888
#define OF_PW2  557952
#define OF_PB2  558016
#define OF_WQ   558080
#define OF_BQ   574464
#define OF_WK   574592
#define OF_BK   590976
#define OF_WV   591104
#define OF_BV   607488
#define OF_WO   607616
#define OF_BO   624000
#define OF_LNG  624128
#define OF_LNB  624256
#define OF_SEGW 624384
#define OF_SEGB 693504
#define ARENA_N 693568
#define TOTCVT2 100053   /* arena convert, FEAT excluded (k9 reads source) */

__device__ __forceinline__ float bf2f(const ushort_t* p){
  return __uint_as_float(((unsigned)(*p)) << 16);
}
__device__ __forceinline__ ushort_t f2bf(float f){
  unsigned u = __float_as_uint(f);
  u += 0x7fffu + ((u >> 16) & 1u);
  return (ushort_t)(u >> 16);
}
__device__ __forceinline__ float unlo(unsigned u){ return __uint_as_float(u << 16); }
__device__ __forceinline__ float unhi(unsigned u){ return __uint_as_float(u & 0xffff0000u); }

struct SrcPtrs { const void* p[25]; };

// segments 1..24 of the original table (FEAT dropped); src = sp.p[s+1]
__device__ const int g_cnt2[24] = {16384,128,128,128,16384,128,192,64,64,64,64,1,
                                   16384,128,16384,128,16384,128,16384,128,128,128,0,20};
__device__ const int g_off2[24] = {OF_CW1,OF_CB1,OF_CG1,OF_CBE1,OF_CW2,OF_CB2,
                                   OF_PW1,OF_PB1,OF_PG1,OF_PBE1,OF_PW2,OF_PB2,
                                   OF_WQ,OF_BQ,OF_WK,OF_BK,OF_WV,OF_BV,OF_WO,OF_BO,
                                   OF_LNG,OF_LNB,OF_SEGW,OF_SEGB};

__device__ __forceinline__ float ldi(const void* p, int off, int fl){
  return fl ? bf2f((const ushort_t*)p + off) : ((const float*)p)[off];
}

struct SPREP {
  float frows[16][CD];     // 8 KB
  float qpart[2][16][CD];  // 16 KB
  float part[8][CD];       // 4 KB
  float cfs[CD];           // 0.5 KB
  float gpart[8][CD];      // 4 KB
};
union __align__(16) UPREP { SPREP sv; int smom[18]; };

// ========== KPREP (512 threads) ==========
__global__ __launch_bounds__(512) void kprep(SrcPtrs sp, const int* idx, int* flag,
    float* arena, float* wt, int* map, float* afold_g, float* scfold_g,
    float* qb, float* t1T)
{
  __shared__ UPREP sm;
  __shared__ int sm_flag;
  int t = threadIdx.x, b = blockIdx.x;
  if (t < 64){
    const ushort_t* f16 = (const ushort_t*)sp.p[0];
    unsigned u = f16[2*t];
    int e = (u >> 7) & 0xFF;
    int sane = (u == 0 || (e >= 90 && e <= 150)) ? 1 : 0;
    unsigned long long bl = __ballot(sane);
    if (t == 0) sm_flag = (__popcll(bl) >= 48) ? 1 : 0;
  }
  __syncthreads();
  const int fl = sm_flag;

  if (b < 255){
    int gid = b*512 + t;
    const int GS = 255*512;
    if (gid == 0) *flag = fl;
    for (int k=gid; k<MAPN; k+=GS) map[k] = -1;
    for (int el=gid; el<TOTCVT2; el+=GS){
      int s=0, rem=el;
      while (rem >= g_cnt2[s]){ rem -= g_cnt2[s]; ++s; }
      arena[g_off2[s]+rem] = ldi(sp.p[s+1], rem, fl);
    }
    for (int k=gid; k<27*NCD*CD; k+=GS){
      int nb = k/(NCD*CD); int rem = k - nb*(NCD*CD); int o = rem/CD, i = rem - o*CD;
      wt[k] = ldi(sp.p[23], nb*(CD*NCD) + i*NCD + o, fl);
    }
  } else if (b < 511){
    int sv = b - 255;
    int rb = sv*16;
    if (fl){
      const uint2* fsrc = (const uint2*)((const ushort_t*)sp.p[0] + (size_t)rb*CD);
      uint2 u = fsrc[t];
      float* dst = &sm.sv.frows[t>>5][(t&31)*4];
      dst[0]=unlo(u.x); dst[1]=unhi(u.x); dst[2]=unlo(u.y); dst[3]=unhi(u.y);
    } else {
      const float4* fsrc = (const float4*)((const float*)sp.p[0] + (size_t)rb*CD);
      ((float4*)sm.sv.frows)[t] = fsrc[t];
    }
    __syncthreads();
    // ---- q-proj: thread = (c8:16, row:16, khalf:2)
    {
      int c8 = (t&15)*8, r = (t>>4)&15, kh = t>>8;
      int i0 = kh*64;
      float acc[8] = {0.f,0.f,0.f,0.f,0.f,0.f,0.f,0.f};
      if (fl){
        const ushort_t* wqp = (const ushort_t*)sp.p[13];
        #pragma unroll 4
        for (int i=i0; i<i0+64; ++i){
          uint4 w4 = *(const uint4*)(wqp + (size_t)i*CD + c8);
          float fr = sm.sv.frows[r][i];
          acc[0] += unlo(w4.x)*fr; acc[1] += unhi(w4.x)*fr;
          acc[2] += unlo(w4.y)*fr; acc[3] += unhi(w4.y)*fr;
          acc[4] += unlo(w4.z)*fr; acc[5] += unhi(w4.z)*fr;
          acc[6] += unlo(w4.w)*fr; acc[7] += unhi(w4.w)*fr;
        }
      } else {
        const float* wqp = (const float*)sp.p[13];
        #pragma unroll 4
        for (int i=i0; i<i0+64; ++i){
          float4 wa = *(const float4*)(wqp + (size_t)i*CD + c8);
          float4 wb = *(const float4*)(wqp + (size_t)i*CD + c8 + 4);
          float fr = sm.sv.frows[r][i];
          acc[0]+=wa.x*fr; acc[1]+=wa.y*fr; acc[2]+=wa.z*fr; acc[3]+=wa.w*fr;
          acc[4]+=wb.x*fr; acc[5]+=wb.y*fr; acc[6]+=wb.z*fr; acc[7]+=wb.w*fr;
        }
      }
      #pragma unroll
      for (int j=0;j<8;++j) sm.sv.qpart[kh][r][c8+j] = acc[j];
    }
    __syncthreads();
    for (int e = t; e < 16*CD; e += 512){
      int r = e>>7, c = e&127;
      qb[(size_t)(rb+r)*CD + c] = sm.sv.qpart[0][r][c] + sm.sv.qpart[1][r][c]
                                + ldi(sp.p[14], c, fl);
    }
    // ---- segment softmax-sum: 8 waves x 2 rows
    {
      int w = t>>6, l = t&63;
      float a0 = 0.f, a1 = 0.f;
      #pragma unroll
      for (int k=0;k<2;++k){
        int r = w*2 + k;
        float f0 = sm.sv.frows[r][l];
        float f1 = sm.sv.frows[r][l+64];
        float m = fmaxf(f0,f1);
        #pragma unroll
        for (int o=32;o;o>>=1) m = fmaxf(m, __shfl_xor(m,o,64));
        float e0 = __expf(f0-m), e1 = __expf(f1-m);
        float ssum = e0+e1;
        #pragma unroll
        for (int o=32;o;o>>=1) ssum += __shfl_xor(ssum,o,64);
        float inv = 1.f/ssum;
        a0 += e0*inv; a1 += e1*inv;
      }
      sm.sv.part[w][l] = a0; sm.sv.part[w][l+64] = a1;
    }
    __syncthreads();
    if (t < CD){
      float s = 0.f;
      #pragma unroll
      for (int w=0;w<8;++w) s += sm.sv.part[w][t];
      sm.sv.cfs[t] = s;
    }
    __syncthreads();
    // ---- GEMV1: thread = (c2:64, kg:8)
    {
      int c2 = (t&63)*2, kg = t>>6;
      int i0 = kg*16;
      float a0 = 0.f, a1 = 0.f;
      if (fl){
        const ushort_t* W = (const ushort_t*)sp.p[1];
        #pragma unroll 4
        for (int i=i0; i<i0+16; ++i){
          unsigned w = *(const unsigned*)(W + (size_t)i*CD + c2);
          float cfv = sm.sv.cfs[i];
          a0 += unlo(w)*cfv; a1 += unhi(w)*cfv;
        }
      } else {
        const float* W = (const float*)sp.p[1];
        #pragma unroll 4
        for (int i=i0; i<i0+16; ++i){
          float2 w = *(const float2*)(W + (size_t)i*CD + c2);
          float cfv = sm.sv.cfs[i];
          a0 += w.x*cfv; a1 += w.y*cfv;
        }
      }
      sm.sv.gpart[kg][c2] = a0; sm.sv.gpart[kg][c2+1] = a1;
    }
    __syncthreads();
    if (t < CD){
      float s = 0.f;
      #pragma unroll
      for (int kg=0;kg<8;++kg) s += sm.sv.gpart[kg][t];
      t1T[(size_t)t*NSV + sv] = s + ldi(sp.p[2], t, fl);
    }
  } else {
    // ---- b == 511: moments + BN fold (wave-reduced, no per-lane LDS atomic storms)
    if (t < 18) sm.smom[t] = 0;
    __syncthreads();
    {
      // voxel moments
      int sacc[9] = {0,0,0,0,0,0,0,0,0};
      for (int v = t; v < NVOX; v += 512){
        int4 q = ((const int4*)idx)[v];
        sacc[0]+=q.y; sacc[1]+=q.z; sacc[2]+=q.w;
        sacc[3]+=q.y*q.y; sacc[4]+=q.z*q.z; sacc[5]+=q.w*q.w;
        sacc[6]+=q.y*q.z; sacc[7]+=q.y*q.w; sacc[8]+=q.z*q.w;
      }
      // supervoxel (cell) moments
      int um[9] = {0,0,0,0,0,0,0,0,0};
      if (t < 256){
        int4 q = ((const int4*)idx)[t*16];
        int gx=q.y>>2, gy=q.z>>2, gz=q.w>>2;
        um[0]=gx; um[1]=gy; um[2]=gz;
        um[3]=gx*gx; um[4]=gy*gy; um[5]=gz*gz;
        um[6]=gx*gy; um[7]=gx*gz; um[8]=gy*gz;
      }
      // 64-lane shuffle tree per moment, one atomic per wave per moment
      int lane = t & 63;
      #pragma unroll
      for (int i=0;i<9;++i){
        int s = sacc[i];
        int u = um[i];
        #pragma unroll
        for (int o=32;o;o>>=1){
          s += __shfl_xor(s, o, 64);
          u += __shfl_xor(u, o, 64);
        }
        if (lane == 0){
          if (s) atomicAdd(&sm.smom[9+i], s);
          if (u) atomicAdd(&sm.smom[i], u);
        }
      }
    }
    __syncthreads();
    if (t < 64){
      int* smom = sm.smom;
      double U1[3]={(double)smom[0],(double)smom[1],(double)smom[2]};
      double S1[3]={(double)smom[9],(double)smom[10],(double)smom[11]};
      double Uxx[3][3], Sxx[3][3];
      Uxx[0][0]=smom[3]; Uxx[1][1]=smom[4]; Uxx[2][2]=smom[5];
      Uxx[0][1]=Uxx[1][0]=smom[6]; Uxx[0][2]=Uxx[2][0]=smom[7]; Uxx[1][2]=Uxx[2][1]=smom[8];
      Sxx[0][0]=smom[12]; Sxx[1][1]=smom[13]; Sxx[2][2]=smom[14];
      Sxx[0][1]=Sxx[1][0]=smom[15]; Sxx[0][2]=Sxx[2][0]=smom[16]; Sxx[1][2]=Sxx[2][1]=smom[17];
      double M1[3], M2[3][3];
      for (int a=0;a<3;++a) M1[a] = 256.0*S1[a] - 4096.0*U1[a];
      for (int a=0;a<3;++a)
        for (int b2=0;b2<3;++b2)
          M2[a][b2] = 256.0*Sxx[a][b2] - S1[a]*U1[b2] - S1[b2]*U1[a] + 4096.0*Uxx[a][b2];
      double wv_[3]={(double)ldi(sp.p[7],t,fl),(double)ldi(sp.p[7],64+t,fl),(double)ldi(sp.p[7],128+t,fl)};
      double bj=(double)ldi(sp.p[8],t,fl), gj=(double)ldi(sp.p[9],t,fl), bej=(double)ldi(sp.p[10],t,fl);
      double Mw=0.0, wMw=0.0;
      for (int a=0;a<3;++a){
        Mw += M1[a]*wv_[a];
        for (int b2=0;b2<3;++b2) wMw += wv_[a]*M2[a][b2]*wv_[b2];
      }
      const double NM = 1048576.0;
      double mean = Mw/NM + bj;
      double Ey2  = wMw/NM + 2.0*bj*Mw/NM + bj*bj;
      double var  = Ey2 - mean*mean;
      double scale = gj / sqrt(var + 1e-5);
      afold_g[t]      = (float)(wv_[0]*scale);
      afold_g[64+t]   = (float)(wv_[1]*scale);
      afold_g[128+t]  = (float)(wv_[2]*scale);
      scfold_g[t]     = (float)(bj*scale + bej - mean*scale);
    }
  }
}

// ========== K6PB: 1024 blocks. b<512: pbias table (8 queries/block).
//            b in [512,1024): k6 GEMVs (role = (b-512)>>8: 0=k, 1=v). ==========
__global__ __launch_bounds__(256) void k6pb(const float* t1T, const float* A,
    const int* idx, int* map, float* kb, float* vb,
    const float* afold_g, const float* scfold_g, float* pbias_b)
{
  __shared__ float saf[3][64];
  __shared__ float ssc[64];
  __shared__ float w2s[64];
  __shared__ __align__(16) float e4q[64][8];
  __shared__ float xs[8], ys[8], zs[8];
  __shared__ float row[CD];
  __shared__ float cpar[2][CD];
  __shared__ float hrow[CD];
  int t = threadIdx.x, b = blockIdx.x;
  if (b < 512){
    // ---- pbias: hoisted 64-iter MLP; layout pbias_b[(b*256+s)*8 + qi]
    if (t < 64){
      saf[0][t] = afold_g[t]; saf[1][t] = afold_g[64+t]; saf[2][t] = afold_g[128+t];
      ssc[t] = scfold_g[t]; w2s[t] = A[OF_PW2+t];
    } else if (t < 72){
      int qi = t - 64;
      int4 q = ((const int4*)idx)[b*8 + qi];
      xs[qi] = (float)q.y; ys[qi] = (float)q.z; zs[qi] = (float)q.w;
    }
    __syncthreads();
    for (int e = t; e < 512; e += 256){
      int j = e & 63, qi = e >> 6;
      e4q[j][qi] = saf[0][j]*xs[qi] + saf[1][j]*ys[qi] + saf[2][j]*zs[qi];
    }
    __syncthreads();
    int4 q0 = ((const int4*)idx)[t*16];
    float ux = (float)(q0.y>>2), uy = (float)(q0.z>>2), uz = (float)(q0.w>>2);
    float pb2 = A[OF_PB2];
    float pbv[8];
    #pragma unroll
    for (int i=0;i<8;++i) pbv[i] = pb2;
    #pragma unroll 2
    for (int j=0;j<64;++j){
      float dj = ssc[j] - (saf[0][j]*ux + saf[1][j]*uy + saf[2][j]*uz);
      float wj = w2s[j];
      float4 e0 = *(const float4*)&e4q[j][0];
      float4 e1 = *(const float4*)&e4q[j][4];
      pbv[0] += fmaxf(e0.x+dj,0.f)*wj; pbv[1] += fmaxf(e0.y+dj,0.f)*wj;
      pbv[2] += fmaxf(e0.z+dj,0.f)*wj; pbv[3] += fmaxf(e0.w+dj,0.f)*wj;
      pbv[4] += fmaxf(e1.x+dj,0.f)*wj; pbv[5] += fmaxf(e1.y+dj,0.f)*wj;
      pbv[6] += fmaxf(e1.z+dj,0.f)*wj; pbv[7] += fmaxf(e1.w+dj,0.f)*wj;
    }
    float* dst = pbias_b + ((size_t)b*256 + t)*8;
    *(float4*)dst       = make_float4(pbv[0],pbv[1],pbv[2],pbv[3]);
    *(float4*)(dst + 4) = make_float4(pbv[4],pbv[5],pbv[6],pbv[7]);
    return;
  }
  // ---- k6: BN-fold + relu + cw2 + {wk|wv} projection for supervoxel s
  int role = (b - 512) >> 8, s = (b - 512) & 255;
  if (role == 0 && t >= 128 && t < 144){
    int v = s*16 + (t-128);
    int4 q = ((const int4*)idx)[v];
    map[((q.x*XD + q.y)*YD + q.z)*ZD + q.w] = v;
  }
  if (t < CD){
    const float4* col = (const float4*)(t1T + (size_t)t*NSV);
    float sum=0.f, sq=0.f;
    #pragma unroll 8
    for (int i=0;i<NSV/4;++i){
      float4 v = col[i];
      sum += v.x+v.y+v.z+v.w;
      sq  += v.x*v.x+v.y*v.y+v.z*v.z+v.w*v.w;
    }
    float mean = sum*(1.f/256.f);
    float var  = sq*(1.f/256.f) - mean*mean;
    float scv = A[OF_CG1+t]*rsqrtf(var+EPSF);
    float shv = A[OF_CBE1+t] - mean*scv;
    row[t] = fmaxf(t1T[(size_t)t*NSV + s]*scv + shv, 0.f);
  }
  __syncthreads();
  int c = t&127, half = t>>7;
  {
    const float* W = A + OF_CW2;
    float acc = 0.f;
    #pragma unroll 8
    for (int i=half*64;i<half*64+64;++i) acc += row[i]*W[i*CD+c];
    cpar[half][c] = acc;
  }
  __syncthreads();
  if (t < CD) hrow[t] = cpar[0][t]+cpar[1][t]+A[OF_CB2+t];
  __syncthreads();
  {
    const float* W = role ? (A+OF_WV) : (A+OF_WK);
    float acc = 0.f;
    #pragma unroll 8
    for (int i=half*64;i<half*64+64;++i) acc += hrow[i]*W[i*CD+c];
    cpar[half][c] = acc;
  }
  __syncthreads();
  if (t < CD){
    float v = cpar[0][t]+cpar[1][t] + (role ? A[OF_BV+t] : A[OF_BK+t]);
    if (role) vb[(size_t)s*CD+t] = v; else kb[(size_t)s*CD+t] = v;
  }
}

// ========== K9 v7: Q=8 queries/block, 512 threads, 512 blocks ==========
// R3 measured per-block fixed cost F ~= 22.5 ns (K/V reads, scf round-trips,
// barrier drains). Halving block count (1024->512) with Q=8 saves ~512*F ~=
// 11 us. 512 threads keep occupancy at 16 waves/CU (2 blocks/CU x 8 waves,
// LDS 56.3 KB): score thread = (sv, head-half); PV = 8 s-octants; wo = 4
// K-quarters over 8 queries. Per-thread work ~= the proven R2 kernel's.
// scf[256][32]: float4 slot = hh*2+(q>>2), col4 = slot ^ (s&7) (bijective
// per row, uniform bank spread). Barrier ordering = R2's proven argument.
__global__ __launch_bounds__(512, 4) void k9_attn(
    const float* A, const int* idx, const float* pbias_b,
    const float* kb, const float* vb, const float* qb,
    const void* featsrc, const int* flag, float* yb)
{
  __shared__ __align__(16) float q8s[8][CD];       // 4 KB [q][c]
  __shared__ __align__(16) float scf[NSV][32];     // 32 KB swizzled probs (4h x 8q)
  __shared__ __align__(16) float ctxT[CD*8];       // 4 KB [c][q] stride 8
  __shared__ __align__(16) float cpart[4096];      // 16 KB (PV: [o][q][c64]; wo: [kq][q][c128])
  __shared__ float rinv[64];                       // [q*8 + h]
  int t = threadIdx.x;
  int n0 = blockIdx.x*8;
  const int fl = *flag;
  if (t < 256) ((float4*)q8s)[t] = ((const float4*)(qb + (size_t)n0*CD))[t];
  int ts = t & 255, hp = t >> 8;
  // pbias for (sv=ts, all 8 queries): two aligned float4s; layout matches kpb
  const float* pbp = pbias_b + ((size_t)blockIdx.x*256 + ts)*8;
  float4 pbq0 = *(const float4*)pbp;
  float4 pbq1 = *(const float4*)(pbp + 4);
  float pb[8] = {pbq0.x,pbq0.y,pbq0.z,pbq0.w, pbq1.x,pbq1.y,pbq1.z,pbq1.w};
  __syncthreads();
  const float4* krow = (const float4*)(kb + (size_t)ts*CD);
  #pragma unroll
  for (int p=0;p<2;++p){
    // ---- scores + exp: thread (ts, hp) handles hh = hp*2, hp*2+1
    {
      #pragma unroll
      for (int u=0; u<2; ++u){
        int hh = hp*2 + u;
        int h = p*4 + hh;
        float4 k0 = krow[h*4+0], k1 = krow[h*4+1], k2 = krow[h*4+2], k3 = krow[h*4+3];
        float pr[8];
        #pragma unroll
        for (int g=0; g<8; ++g){
          const float4* qg4 = (const float4*)&q8s[g][h*DHD];
          float4 qa = qg4[0], qbv = qg4[1], qc = qg4[2], qd = qg4[3];
          float dot = qa.x*k0.x + qa.y*k0.y + qa.z*k0.z + qa.w*k0.w
                    + qbv.x*k1.x + qbv.y*k1.y + qbv.z*k1.z + qbv.w*k1.w
                    + qc.x*k2.x + qc.y*k2.y + qc.z*k2.z + qc.w*k2.w
                    + qd.x*k3.x + qd.y*k3.y + qd.z*k3.z + qd.w*k3.w;
          pr[g] = __expf(dot*0.25f + pb[g]);
        }
        int c4a = (hh*2+0) ^ (ts&7);
        int c4b = (hh*2+1) ^ (ts&7);
        *(float4*)&scf[ts][c4a*4] = make_float4(pr[0],pr[1],pr[2],pr[3]);
        *(float4*)&scf[ts][c4b*4] = make_float4(pr[4],pr[5],pr[6],pr[7]);
      }
    }
    __syncthreads();
    // ---- denominators: wave w = query w (8 waves), 4 heads each
    {
      int w = t>>6, lane = t&63;
      int qg = w>>2, j = w&3;
      #pragma unroll
      for (int hh=0; hh<4; ++hh){
        int slot = hh*2 + qg;
        float s0 = 0.f;
        #pragma unroll
        for (int k=0;k<4;++k){
          int r = lane + 64*k;
          s0 += scf[r][(slot ^ (r&7))*4 + j];
        }
        #pragma unroll
        for (int o=32;o;o>>=1) s0 += __shfl_xor(s0,o,64);
        if (lane==0) rinv[w*8 + p*4 + hh] = 1.f/s0;
      }
    }
    // ---- PV: thread (octant o = t>>6, channel c = t&63) of pass channels
    {
      int o = t>>6, c = t&63, hh = c>>4;
      const float* vcol = vb + p*64 + c;
      float a[8] = {0.f,0.f,0.f,0.f,0.f,0.f,0.f,0.f};
      int sA = hh*2+0, sB = hh*2+1;
      #pragma unroll 4
      for (int s=o*32; s<o*32+32; ++s){
        float v = vcol[(size_t)s*CD];
        float4 pvA = *(const float4*)&scf[s][(sA ^ (s&7))*4];
        float4 pvB = *(const float4*)&scf[s][(sB ^ (s&7))*4];
        a[0] += pvA.x*v; a[1] += pvA.y*v; a[2] += pvA.z*v; a[3] += pvA.w*v;
        a[4] += pvB.x*v; a[5] += pvB.y*v; a[6] += pvB.z*v; a[7] += pvB.w*v;
      }
      #pragma unroll
      for (int g=0;g<8;++g) cpart[o*512 + g*64 + c] = a[g];
    }
    __syncthreads();
    // ---- assemble: thread (q = t>>6, c = t&63) -> ctxT[(p*64+c)*8 + q]
    {
      int g = t>>6, c = t&63;
      float s = 0.f;
      #pragma unroll
      for (int o=0;o<8;++o) s += cpart[o*512 + g*64 + c];
      ctxT[(p*64+c)*8 + g] = s * rinv[g*8 + p*4 + (c>>4)];
    }
    // no barrier: next pass's scf writes are ordered after this pass's scf
    // reads by the post-PV barrier; next pass's cpart writes happen only
    // after its own post-score barrier (orders these cpart reads).
  }
  __syncthreads();
  // ---- wo: thread (kq = t>>7, c = t&127); K split in 4 quarters of 32
  {
    int kq = t>>7, c = t&127;
    const float* wo = A + OF_WO;
    float acc[8] = {0.f,0.f,0.f,0.f,0.f,0.f,0.f,0.f};
    #pragma unroll 4
    for (int i=kq*32; i<kq*32+32; ++i){
      float wv = wo[i*CD+c];
      float4 r0 = *(const float4*)&ctxT[i*8];
      float4 r1 = *(const float4*)&ctxT[i*8+4];
      acc[0]+=r0.x*wv; acc[1]+=r0.y*wv; acc[2]+=r0.z*wv; acc[3]+=r0.w*wv;
      acc[4]+=r1.x*wv; acc[5]+=r1.y*wv; acc[6]+=r1.z*wv; acc[7]+=r1.w*wv;
    }
    #pragma unroll
    for (int g=0;g<8;++g) cpart[kq*1024 + g*128 + c] = acc[g];
  }
  __syncthreads();
  if (t < CD){
    float bov = A[OF_BO+t];
    #pragma unroll
    for (int g=0;g<8;++g){
      float fv = fl ? bf2f((const ushort_t*)featsrc + (size_t)(n0+g)*CD + t)
                    : ((const float*)featsrc)[(size_t)(n0+g)*CD + t];
      ctxT[t*8+g] = cpart[g*128+t] + cpart[1024+g*128+t] + cpart[2048+g*128+t]
                  + cpart[3072+g*128+t] + bov + fv;
    }
  }
  __syncthreads();
  // ---- LayerNorm: wave g handles query g (8 waves, all used)
  {
    int g = t>>6, lane = t&63;
    float x0 = ctxT[lane*8+g], x1 = ctxT[(lane+64)*8+g];
    float s1 = x0+x1, s2 = x0*x0+x1*x1;
    #pragma unroll
    for (int o=32;o;o>>=1){ s1 += __shfl_xor(s1,o,64); s2 += __shfl_xor(s2,o,64); }
    float mean = s1*(1.f/128.f);
    float var  = s2*(1.f/128.f) - mean*mean;
    float rs = rsqrtf(var + EPSF);
    yb[(size_t)(n0+g)*CD + lane]    = (x0-mean)*rs*A[OF_LNG+lane]    + A[OF_LNB+lane];
    yb[(size_t)(n0+g)*CD + lane+64] = (x1-mean)*rs*A[OF_LNG+lane+64] + A[OF_LNB+lane+64];
  }
}

// ========== K10: SubMConv3d, 8 voxels/block (512 blocks), weights hoisted ==========
__global__ __launch_bounds__(256) void k10_conv(const int* idx, const int* map,
    const float* yb, const float* A, const float* wt, const int* flag, void* outv)
{
  __shared__ int sco4[8][4];
  __shared__ int jn[8][27];
  __shared__ float partial[4][8][NCD];
  int t = threadIdx.x;
  int p0 = blockIdx.x*8;
  if (t < 32) ((int*)sco4)[t] = idx[4*p0 + t];
  __syncthreads();
  if (t < 216){
    int v = t/27, nb = t - v*27;
    int kd = nb/9, kh = (nb/3)%3, kw = nb%3;
    int bb = sco4[v][0];
    int nx = sco4[v][1]+kd-1, ny = sco4[v][2]+kh-1, nz = sco4[v][3]+kw-1;
    int j = -1;
    if ((unsigned)nx < XD && (unsigned)ny < YD && (unsigned)nz < ZD)
      j = map[((bb*XD+nx)*YD+ny)*ZD+nz];
    jn[v][nb] = j;
  }
  __syncthreads();
  int w = t>>6, l = t&63;
  int og = l & 3, cg = l >> 2;
  int c0 = cg*8;
  float acc[8][5];
  #pragma unroll
  for (int v=0;v<8;++v)
    #pragma unroll
    for (int oo=0;oo<5;++oo) acc[v][oo]=0.f;
  for (int nb = w; nb < 27; nb += 4){
    const float* wbase = wt + (size_t)nb*NCD*CD + c0;
    float4 wreg[10];
    #pragma unroll
    for (int oo=0;oo<5;++oo){
      wreg[oo*2]   = *(const float4*)(wbase + (size_t)(og*5+oo)*CD);
      wreg[oo*2+1] = *(const float4*)(wbase + (size_t)(og*5+oo)*CD + 4);
    }
    #pragma unroll
    for (int v=0; v<8; ++v){
      int j = jn[v][nb];
      if (j < 0) continue;
      const float4* y4 = (const float4*)(yb + (size_t)j*CD + c0);
      float4 ya = y4[0], ybb = y4[1];
      #pragma unroll
      for (int oo=0;oo<5;++oo){
        float4 wa = wreg[oo*2], wb = wreg[oo*2+1];
        acc[v][oo] += ya.x*wa.x + ya.y*wa.y + ya.z*wa.z + ya.w*wa.w
                    + ybb.x*wb.x + ybb.y*wb.y + ybb.z*wb.z + ybb.w*wb.w;
      }
    }
  }
  #pragma unroll
  for (int v=0;v<8;++v)
    #pragma unroll
    for (int oo=0;oo<5;++oo){
      float s = acc[v][oo];
      s += __shfl_xor(s, 4, 64);
      s += __shfl_xor(s, 8, 64);
      s += __shfl_xor(s, 16, 64);
      s += __shfl_xor(s, 32, 64);
      if (cg == 0) partial[w][v][og*5+oo] = s;
    }
  __syncthreads();
  if (t < 160){
    int v = t/20, o = t - v*20;
    float s = partial[0][v][o]+partial[1][v][o]+partial[2][v][o]+partial[3][v][o]
            + A[OF_SEGB+o];
    if (*flag) ((ushort_t*)outv)[(size_t)(p0+v)*NCD + o] = f2bf(s);
    else       ((float*)outv)[(size_t)(p0+v)*NCD + o]   = s;
  }
}

// ---------------- launch ----------------
extern "C" void kernel_launch(void* const* d_in, const int* in_sizes, int n_in,
                              void* d_out, int out_size, void* d_ws, size_t ws_size,
                              hipStream_t stream) {
  const int* idx = (const int*)d_in[0];

  char* w = (char*)d_ws;
  size_t off = 0;
  #define ALLOC(name, type, count) \
    type* name = (type*)(w + off); off += (((size_t)(count)*sizeof(type)) + 255) & ~(size_t)255;
  ALLOC(flag,   int,   64)
  ALLOC(arena,  float, ARENA_N)
  ALLOC(wt,     float, 27*NCD*CD)
  ALLOC(map,    int,   MAPN)
  ALLOC(afold,  float, 192)
  ALLOC(scfold, float, 64)
  ALLOC(t1T,    float, CD*NSV)
  ALLOC(kb,     float, NSV*CD)
  ALLOC(vbuf,   float, NSV*CD)
  ALLOC(qb,     float, NVOX*CD)
  ALLOC(yb,     float, NVOX*CD)
  ALLOC(pbias_b,float, 512*256*8)
  #undef ALLOC
  (void)off; (void)ws_size; (void)n_in; (void)in_sizes; (void)out_size;

  SrcPtrs sp;
  for (int i=0;i<25;++i) sp.p[i] = d_in[i+1];

  kprep   <<<512, 512, 0, stream>>>(sp, idx, flag, arena, wt, map, afold, scfold, qb, t1T);
  k6pb    <<<1024, 256, 0, stream>>>(t1T, arena, idx, map, kb, vbuf, afold, scfold, pbias_b);
  k9_attn <<<NVOX/8, 512, 0, stream>>>(arena, idx, pbias_b, kb, vbuf, qb, d_in[1], flag, yb);
  k10_conv<<<NVOX/8, 256, 0, stream>>>(idx, map, yb, arena, wt, flag, d_out);
}

// Round 8
// 190.523 us; speedup vs baseline: 1.0936x; 1.0363x over previous
//
#include <hip/hip_runtime.h>

typedef unsigned short ushort_t;

#define NVOX 4096
#define NSV  256
#define XD   128
#define YD   128
#define ZD   16
#define CD   128
#define NCD  20
#define HD   8
#define DHD  16
#define MAPN 524288
#define EPSF 1e-5f

// ---- fp32 arena offsets (floats) ----
#define OF_FEAT 0
#define OF_CW1  524288
#define OF_CB1  540672
#define OF_CG1  540800
#define OF_CBE1 540928
#define OF_CW2  541056
#define OF_CB2  557440
#define OF_PW1  557568
#define OF_PB1  557760
#define OF_PG1  557824
#define OF_PBE1 557888
#define OF_PW2  557952
#define OF_PB2  558016
#define OF_WQ   558080
#define OF_BQ   574464
#define OF_WK   574592
#define OF_BK   590976
#define OF_WV   591104
#define OF_BV   607488
#define OF_WO   607616
#define OF_BO   624000
#define OF_LNG  624128
#define OF_LNB  624256
#define OF_SEGW 624384
#define OF_SEGB 693504
#define ARENA_N 693568
#define TOTCVT2 100053   /* arena convert, FEAT excluded (k9 reads source) */

__device__ __forceinline__ float bf2f(const ushort_t* p){
  return __uint_as_float(((unsigned)(*p)) << 16);
}
__device__ __forceinline__ ushort_t f2bf(float f){
  unsigned u = __float_as_uint(f);
  u += 0x7fffu + ((u >> 16) & 1u);
  return (ushort_t)(u >> 16);
}
__device__ __forceinline__ float unlo(unsigned u){ return __uint_as_float(u << 16); }
__device__ __forceinline__ float unhi(unsigned u){ return __uint_as_float(u & 0xffff0000u); }

struct SrcPtrs { const void* p[25]; };

// segments 1..24 of the original table (FEAT dropped); src = sp.p[s+1]
__device__ const int g_cnt2[24] = {16384,128,128,128,16384,128,192,64,64,64,64,1,
                                   16384,128,16384,128,16384,128,16384,128,128,128,0,20};
__device__ const int g_off2[24] = {OF_CW1,OF_CB1,OF_CG1,OF_CBE1,OF_CW2,OF_CB2,
                                   OF_PW1,OF_PB1,OF_PG1,OF_PBE1,OF_PW2,OF_PB2,
                                   OF_WQ,OF_BQ,OF_WK,OF_BK,OF_WV,OF_BV,OF_WO,OF_BO,
                                   OF_LNG,OF_LNB,OF_SEGW,OF_SEGB};

__device__ __forceinline__ float ldi(const void* p, int off, int fl){
  return fl ? bf2f((const ushort_t*)p + off) : ((const float*)p)[off];
}

struct SPREP {
  float frows[16][CD];     // 8 KB
  float qpart[2][16][CD];  // 16 KB
  float part[8][CD];       // 4 KB
  float cfs[CD];           // 0.5 KB
  float gpart[8][CD];      // 4 KB
};
union __align__(16) UPREP { SPREP sv; int smom[18]; };

// ========== KPREP (512 threads) ==========
__global__ __launch_bounds__(512) void kprep(SrcPtrs sp, const int* idx, int* flag,
    float* arena, float* wt, int* map, float* afold_g, float* scfold_g,
    float* qb, float* t1T)
{
  __shared__ UPREP sm;
  __shared__ int sm_flag;
  int t = threadIdx.x, b = blockIdx.x;
  if (t < 64){
    const ushort_t* f16 = (const ushort_t*)sp.p[0];
    unsigned u = f16[2*t];
    int e = (u >> 7) & 0xFF;
    int sane = (u == 0 || (e >= 90 && e <= 150)) ? 1 : 0;
    unsigned long long bl = __ballot(sane);
    if (t == 0) sm_flag = (__popcll(bl) >= 48) ? 1 : 0;
  }
  __syncthreads();
  const int fl = sm_flag;

  if (b < 255){
    int gid = b*512 + t;
    const int GS = 255*512;
    if (gid == 0) *flag = fl;
    for (int k=gid; k<MAPN; k+=GS) map[k] = -1;
    for (int el=gid; el<TOTCVT2; el+=GS){
      int s=0, rem=el;
      while (rem >= g_cnt2[s]){ rem -= g_cnt2[s]; ++s; }
      arena[g_off2[s]+rem] = ldi(sp.p[s+1], rem, fl);
    }
    for (int k=gid; k<27*NCD*CD; k+=GS){
      int nb = k/(NCD*CD); int rem = k - nb*(NCD*CD); int o = rem/CD, i = rem - o*CD;
      wt[k] = ldi(sp.p[23], nb*(CD*NCD) + i*NCD + o, fl);
    }
  } else if (b < 511){
    int sv = b - 255;
    int rb = sv*16;
    if (fl){
      const uint2* fsrc = (const uint2*)((const ushort_t*)sp.p[0] + (size_t)rb*CD);
      uint2 u = fsrc[t];
      float* dst = &sm.sv.frows[t>>5][(t&31)*4];
      dst[0]=unlo(u.x); dst[1]=unhi(u.x); dst[2]=unlo(u.y); dst[3]=unhi(u.y);
    } else {
      const float4* fsrc = (const float4*)((const float*)sp.p[0] + (size_t)rb*CD);
      ((float4*)sm.sv.frows)[t] = fsrc[t];
    }
    __syncthreads();
    // ---- q-proj: thread = (c8:16, row:16, khalf:2)
    {
      int c8 = (t&15)*8, r = (t>>4)&15, kh = t>>8;
      int i0 = kh*64;
      float acc[8] = {0.f,0.f,0.f,0.f,0.f,0.f,0.f,0.f};
      if (fl){
        const ushort_t* wqp = (const ushort_t*)sp.p[13];
        #pragma unroll 4
        for (int i=i0; i<i0+64; ++i){
          uint4 w4 = *(const uint4*)(wqp + (size_t)i*CD + c8);
          float fr = sm.sv.frows[r][i];
          acc[0] += unlo(w4.x)*fr; acc[1] += unhi(w4.x)*fr;
          acc[2] += unlo(w4.y)*fr; acc[3] += unhi(w4.y)*fr;
          acc[4] += unlo(w4.z)*fr; acc[5] += unhi(w4.z)*fr;
          acc[6] += unlo(w4.w)*fr; acc[7] += unhi(w4.w)*fr;
        }
      } else {
        const float* wqp = (const float*)sp.p[13];
        #pragma unroll 4
        for (int i=i0; i<i0+64; ++i){
          float4 wa = *(const float4*)(wqp + (size_t)i*CD + c8);
          float4 wb = *(const float4*)(wqp + (size_t)i*CD + c8 + 4);
          float fr = sm.sv.frows[r][i];
          acc[0]+=wa.x*fr; acc[1]+=wa.y*fr; acc[2]+=wa.z*fr; acc[3]+=wa.w*fr;
          acc[4]+=wb.x*fr; acc[5]+=wb.y*fr; acc[6]+=wb.z*fr; acc[7]+=wb.w*fr;
        }
      }
      #pragma unroll
      for (int j=0;j<8;++j) sm.sv.qpart[kh][r][c8+j] = acc[j];
    }
    __syncthreads();
    for (int e = t; e < 16*CD; e += 512){
      int r = e>>7, c = e&127;
      qb[(size_t)(rb+r)*CD + c] = sm.sv.qpart[0][r][c] + sm.sv.qpart[1][r][c]
                                + ldi(sp.p[14], c, fl);
    }
    // ---- segment softmax-sum: 8 waves x 2 rows
    {
      int w = t>>6, l = t&63;
      float a0 = 0.f, a1 = 0.f;
      #pragma unroll
      for (int k=0;k<2;++k){
        int r = w*2 + k;
        float f0 = sm.sv.frows[r][l];
        float f1 = sm.sv.frows[r][l+64];
        float m = fmaxf(f0,f1);
        #pragma unroll
        for (int o=32;o;o>>=1) m = fmaxf(m, __shfl_xor(m,o,64));
        float e0 = __expf(f0-m), e1 = __expf(f1-m);
        float ssum = e0+e1;
        #pragma unroll
        for (int o=32;o;o>>=1) ssum += __shfl_xor(ssum,o,64);
        float inv = 1.f/ssum;
        a0 += e0*inv; a1 += e1*inv;
      }
      sm.sv.part[w][l] = a0; sm.sv.part[w][l+64] = a1;
    }
    __syncthreads();
    if (t < CD){
      float s = 0.f;
      #pragma unroll
      for (int w=0;w<8;++w) s += sm.sv.part[w][t];
      sm.sv.cfs[t] = s;
    }
    __syncthreads();
    // ---- GEMV1: thread = (c2:64, kg:8)
    {
      int c2 = (t&63)*2, kg = t>>6;
      int i0 = kg*16;
      float a0 = 0.f, a1 = 0.f;
      if (fl){
        const ushort_t* W = (const ushort_t*)sp.p[1];
        #pragma unroll 4
        for (int i=i0; i<i0+16; ++i){
          unsigned w = *(const unsigned*)(W + (size_t)i*CD + c2);
          float cfv = sm.sv.cfs[i];
          a0 += unlo(w)*cfv; a1 += unhi(w)*cfv;
        }
      } else {
        const float* W = (const float*)sp.p[1];
        #pragma unroll 4
        for (int i=i0; i<i0+16; ++i){
          float2 w = *(const float2*)(W + (size_t)i*CD + c2);
          float cfv = sm.sv.cfs[i];
          a0 += w.x*cfv; a1 += w.y*cfv;
        }
      }
      sm.sv.gpart[kg][c2] = a0; sm.sv.gpart[kg][c2+1] = a1;
    }
    __syncthreads();
    if (t < CD){
      float s = 0.f;
      #pragma unroll
      for (int kg=0;kg<8;++kg) s += sm.sv.gpart[kg][t];
      t1T[(size_t)t*NSV + sv] = s + ldi(sp.p[2], t, fl);
    }
  } else {
    // ---- b == 511: moments + BN fold (wave-reduced, no per-lane LDS atomic storms)
    if (t < 18) sm.smom[t] = 0;
    __syncthreads();
    {
      // voxel moments
      int sacc[9] = {0,0,0,0,0,0,0,0,0};
      for (int v = t; v < NVOX; v += 512){
        int4 q = ((const int4*)idx)[v];
        sacc[0]+=q.y; sacc[1]+=q.z; sacc[2]+=q.w;
        sacc[3]+=q.y*q.y; sacc[4]+=q.z*q.z; sacc[5]+=q.w*q.w;
        sacc[6]+=q.y*q.z; sacc[7]+=q.y*q.w; sacc[8]+=q.z*q.w;
      }
      // supervoxel (cell) moments
      int um[9] = {0,0,0,0,0,0,0,0,0};
      if (t < 256){
        int4 q = ((const int4*)idx)[t*16];
        int gx=q.y>>2, gy=q.z>>2, gz=q.w>>2;
        um[0]=gx; um[1]=gy; um[2]=gz;
        um[3]=gx*gx; um[4]=gy*gy; um[5]=gz*gz;
        um[6]=gx*gy; um[7]=gx*gz; um[8]=gy*gz;
      }
      // 64-lane shuffle tree per moment, one atomic per wave per moment
      int lane = t & 63;
      #pragma unroll
      for (int i=0;i<9;++i){
        int s = sacc[i];
        int u = um[i];
        #pragma unroll
        for (int o=32;o;o>>=1){
          s += __shfl_xor(s, o, 64);
          u += __shfl_xor(u, o, 64);
        }
        if (lane == 0){
          if (s) atomicAdd(&sm.smom[9+i], s);
          if (u) atomicAdd(&sm.smom[i], u);
        }
      }
    }
    __syncthreads();
    if (t < 64){
      int* smom = sm.smom;
      double U1[3]={(double)smom[0],(double)smom[1],(double)smom[2]};
      double S1[3]={(double)smom[9],(double)smom[10],(double)smom[11]};
      double Uxx[3][3], Sxx[3][3];
      Uxx[0][0]=smom[3]; Uxx[1][1]=smom[4]; Uxx[2][2]=smom[5];
      Uxx[0][1]=Uxx[1][0]=smom[6]; Uxx[0][2]=Uxx[2][0]=smom[7]; Uxx[1][2]=Uxx[2][1]=smom[8];
      Sxx[0][0]=smom[12]; Sxx[1][1]=smom[13]; Sxx[2][2]=smom[14];
      Sxx[0][1]=Sxx[1][0]=smom[15]; Sxx[0][2]=Sxx[2][0]=smom[16]; Sxx[1][2]=Sxx[2][1]=smom[17];
      double M1[3], M2[3][3];
      for (int a=0;a<3;++a) M1[a] = 256.0*S1[a] - 4096.0*U1[a];
      for (int a=0;a<3;++a)
        for (int b2=0;b2<3;++b2)
          M2[a][b2] = 256.0*Sxx[a][b2] - S1[a]*U1[b2] - S1[b2]*U1[a] + 4096.0*Uxx[a][b2];
      double wv_[3]={(double)ldi(sp.p[7],t,fl),(double)ldi(sp.p[7],64+t,fl),(double)ldi(sp.p[7],128+t,fl)};
      double bj=(double)ldi(sp.p[8],t,fl), gj=(double)ldi(sp.p[9],t,fl), bej=(double)ldi(sp.p[10],t,fl);
      double Mw=0.0, wMw=0.0;
      for (int a=0;a<3;++a){
        Mw += M1[a]*wv_[a];
        for (int b2=0;b2<3;++b2) wMw += wv_[a]*M2[a][b2]*wv_[b2];
      }
      const double NM = 1048576.0;
      double mean = Mw/NM + bj;
      double Ey2  = wMw/NM + 2.0*bj*Mw/NM + bj*bj;
      double var  = Ey2 - mean*mean;
      double scale = gj / sqrt(var + 1e-5);
      afold_g[t]      = (float)(wv_[0]*scale);
      afold_g[64+t]   = (float)(wv_[1]*scale);
      afold_g[128+t]  = (float)(wv_[2]*scale);
      scfold_g[t]     = (float)(bj*scale + bej - mean*scale);
    }
  }
}

// ========== K6PB: 1024 blocks. b<512: pbias table (8 queries/block).
//            b in [512,1024): k6 GEMVs (role = (b-512)>>8: 0=k, 1=v). ==========
__global__ __launch_bounds__(256) void k6pb(const float* t1T, const float* A,
    const int* idx, int* map, float* kb, float* vb,
    const float* afold_g, const float* scfold_g, float* pbias_b)
{
  __shared__ float saf[3][64];
  __shared__ float ssc[64];
  __shared__ float w2s[64];
  __shared__ __align__(16) float e4q[64][8];
  __shared__ float xs[8], ys[8], zs[8];
  __shared__ float row[CD];
  __shared__ float cpar[2][CD];
  __shared__ float hrow[CD];
  int t = threadIdx.x, b = blockIdx.x;
  if (b < 512){
    // ---- pbias: hoisted 64-iter MLP; layout pbias_b[(b*256+s)*8 + qi]
    if (t < 64){
      saf[0][t] = afold_g[t]; saf[1][t] = afold_g[64+t]; saf[2][t] = afold_g[128+t];
      ssc[t] = scfold_g[t]; w2s[t] = A[OF_PW2+t];
    } else if (t < 72){
      int qi = t - 64;
      int4 q = ((const int4*)idx)[b*8 + qi];
      xs[qi] = (float)q.y; ys[qi] = (float)q.z; zs[qi] = (float)q.w;
    }
    __syncthreads();
    for (int e = t; e < 512; e += 256){
      int j = e & 63, qi = e >> 6;
      e4q[j][qi] = saf[0][j]*xs[qi] + saf[1][j]*ys[qi] + saf[2][j]*zs[qi];
    }
    __syncthreads();
    int4 q0 = ((const int4*)idx)[t*16];
    float ux = (float)(q0.y>>2), uy = (float)(q0.z>>2), uz = (float)(q0.w>>2);
    float pb2 = A[OF_PB2];
    float pbv[8];
    #pragma unroll
    for (int i=0;i<8;++i) pbv[i] = pb2;
    #pragma unroll 2
    for (int j=0;j<64;++j){
      float dj = ssc[j] - (saf[0][j]*ux + saf[1][j]*uy + saf[2][j]*uz);
      float wj = w2s[j];
      float4 e0 = *(const float4*)&e4q[j][0];
      float4 e1 = *(const float4*)&e4q[j][4];
      pbv[0] += fmaxf(e0.x+dj,0.f)*wj; pbv[1] += fmaxf(e0.y+dj,0.f)*wj;
      pbv[2] += fmaxf(e0.z+dj,0.f)*wj; pbv[3] += fmaxf(e0.w+dj,0.f)*wj;
      pbv[4] += fmaxf(e1.x+dj,0.f)*wj; pbv[5] += fmaxf(e1.y+dj,0.f)*wj;
      pbv[6] += fmaxf(e1.z+dj,0.f)*wj; pbv[7] += fmaxf(e1.w+dj,0.f)*wj;
    }
    float* dst = pbias_b + ((size_t)b*256 + t)*8;
    *(float4*)dst       = make_float4(pbv[0],pbv[1],pbv[2],pbv[3]);
    *(float4*)(dst + 4) = make_float4(pbv[4],pbv[5],pbv[6],pbv[7]);
    return;
  }
  // ---- k6: BN-fold + relu + cw2 + {wk|wv} projection for supervoxel s
  int role = (b - 512) >> 8, s = (b - 512) & 255;
  if (role == 0 && t >= 128 && t < 144){
    int v = s*16 + (t-128);
    int4 q = ((const int4*)idx)[v];
    map[((q.x*XD + q.y)*YD + q.z)*ZD + q.w] = v;
  }
  if (t < CD){
    const float4* col = (const float4*)(t1T + (size_t)t*NSV);
    float sum=0.f, sq=0.f;
    #pragma unroll 8
    for (int i=0;i<NSV/4;++i){
      float4 v = col[i];
      sum += v.x+v.y+v.z+v.w;
      sq  += v.x*v.x+v.y*v.y+v.z*v.z+v.w*v.w;
    }
    float mean = sum*(1.f/256.f);
    float var  = sq*(1.f/256.f) - mean*mean;
    float scv = A[OF_CG1+t]*rsqrtf(var+EPSF);
    float shv = A[OF_CBE1+t] - mean*scv;
    row[t] = fmaxf(t1T[(size_t)t*NSV + s]*scv + shv, 0.f);
  }
  __syncthreads();
  int c = t&127, half = t>>7;
  {
    const float* W = A + OF_CW2;
    float acc = 0.f;
    #pragma unroll 8
    for (int i=half*64;i<half*64+64;++i) acc += row[i]*W[i*CD+c];
    cpar[half][c] = acc;
  }
  __syncthreads();
  if (t < CD) hrow[t] = cpar[0][t]+cpar[1][t]+A[OF_CB2+t];
  __syncthreads();
  {
    const float* W = role ? (A+OF_WV) : (A+OF_WK);
    float acc = 0.f;
    #pragma unroll 8
    for (int i=half*64;i<half*64+64;++i) acc += hrow[i]*W[i*CD+c];
    cpar[half][c] = acc;
  }
  __syncthreads();
  if (t < CD){
    float v = cpar[0][t]+cpar[1][t] + (role ? A[OF_BV+t] : A[OF_BK+t]);
    if (role) vb[(size_t)s*CD+t] = v; else kb[(size_t)s*CD+t] = v;
  }
}

// ========== K9 v8: v7 + waveized residual/LN tail (one fewer barrier) ==========
// k9 is barrier/phase-drain bound (FLOP content ~2 us at peak issue vs ~27 us
// measured; VALUBusy plateau ~40% across 25-66% occupancy). v8 cuts the tail:
// wo's cpart[kq][g][c] layout lets wave g form query g's residual directly in
// registers and flow into the in-wave shuffle LN -- removes one barrier, a
// 256w/512r LDS round-trip, and a 2-active-wave phase. Residual feature loads
// are issued at kernel start to hide HBM/L2 latency under the attention body.
__global__ __launch_bounds__(512, 4) void k9_attn(
    const float* A, const int* idx, const float* pbias_b,
    const float* kb, const float* vb, const float* qb,
    const void* featsrc, const int* flag, float* yb)
{
  __shared__ __align__(16) float q8s[8][CD];       // 4 KB [q][c]
  __shared__ __align__(16) float scf[NSV][32];     // 32 KB swizzled probs (4h x 8q)
  __shared__ __align__(16) float ctxT[CD*8];       // 4 KB [c][q] stride 8
  __shared__ __align__(16) float cpart[4096];      // 16 KB (PV: [o][q][c64]; wo: [kq][q][c128])
  __shared__ float rinv[64];                       // [q*8 + h]
  int t = threadIdx.x;
  int n0 = blockIdx.x*8;
  const int fl = *flag;
  if (t < 256) ((float4*)q8s)[t] = ((const float4*)(qb + (size_t)n0*CD))[t];
  int ts = t & 255, hp = t >> 8;
  // pbias for (sv=ts, all 8 queries): two aligned float4s; layout matches kpb
  const float* pbp = pbias_b + ((size_t)blockIdx.x*256 + ts)*8;
  float4 pbq0 = *(const float4*)pbp;
  float4 pbq1 = *(const float4*)(pbp + 4);
  float pb[8] = {pbq0.x,pbq0.y,pbq0.z,pbq0.w, pbq1.x,pbq1.y,pbq1.z,pbq1.w};
  // early-issue residual feature loads for the tail (wave g, lanes = channels)
  int gq = t>>6, lane = t&63;
  float fres0, fres1;
  if (fl){
    fres0 = bf2f((const ushort_t*)featsrc + (size_t)(n0+gq)*CD + lane);
    fres1 = bf2f((const ushort_t*)featsrc + (size_t)(n0+gq)*CD + lane + 64);
  } else {
    fres0 = ((const float*)featsrc)[(size_t)(n0+gq)*CD + lane];
    fres1 = ((const float*)featsrc)[(size_t)(n0+gq)*CD + lane + 64];
  }
  __syncthreads();
  const float4* krow = (const float4*)(kb + (size_t)ts*CD);
  #pragma unroll
  for (int p=0;p<2;++p){
    // ---- scores + exp: thread (ts, hp) handles hh = hp*2, hp*2+1
    {
      #pragma unroll
      for (int u=0; u<2; ++u){
        int hh = hp*2 + u;
        int h = p*4 + hh;
        float4 k0 = krow[h*4+0], k1 = krow[h*4+1], k2 = krow[h*4+2], k3 = krow[h*4+3];
        float pr[8];
        #pragma unroll
        for (int g=0; g<8; ++g){
          const float4* qg4 = (const float4*)&q8s[g][h*DHD];
          float4 qa = qg4[0], qbv = qg4[1], qc = qg4[2], qd = qg4[3];
          float dot = qa.x*k0.x + qa.y*k0.y + qa.z*k0.z + qa.w*k0.w
                    + qbv.x*k1.x + qbv.y*k1.y + qbv.z*k1.z + qbv.w*k1.w
                    + qc.x*k2.x + qc.y*k2.y + qc.z*k2.z + qc.w*k2.w
                    + qd.x*k3.x + qd.y*k3.y + qd.z*k3.z + qd.w*k3.w;
          pr[g] = __expf(dot*0.25f + pb[g]);
        }
        int c4a = (hh*2+0) ^ (ts&7);
        int c4b = (hh*2+1) ^ (ts&7);
        *(float4*)&scf[ts][c4a*4] = make_float4(pr[0],pr[1],pr[2],pr[3]);
        *(float4*)&scf[ts][c4b*4] = make_float4(pr[4],pr[5],pr[6],pr[7]);
      }
    }
    __syncthreads();
    // ---- denominators: wave w = query w (8 waves), 4 heads each
    {
      int w = t>>6;
      int qg = w>>2, j = w&3;
      #pragma unroll
      for (int hh=0; hh<4; ++hh){
        int slot = hh*2 + qg;
        float s0 = 0.f;
        #pragma unroll
        for (int k=0;k<4;++k){
          int r = lane + 64*k;
          s0 += scf[r][(slot ^ (r&7))*4 + j];
        }
        #pragma unroll
        for (int o=32;o;o>>=1) s0 += __shfl_xor(s0,o,64);
        if (lane==0) rinv[w*8 + p*4 + hh] = 1.f/s0;
      }
    }
    // ---- PV: thread (octant o = t>>6, channel c = t&63) of pass channels
    {
      int o = t>>6, c = t&63, hh = c>>4;
      const float* vcol = vb + p*64 + c;
      float a[8] = {0.f,0.f,0.f,0.f,0.f,0.f,0.f,0.f};
      int sA = hh*2+0, sB = hh*2+1;
      #pragma unroll 4
      for (int s=o*32; s<o*32+32; ++s){
        float v = vcol[(size_t)s*CD];
        float4 pvA = *(const float4*)&scf[s][(sA ^ (s&7))*4];
        float4 pvB = *(const float4*)&scf[s][(sB ^ (s&7))*4];
        a[0] += pvA.x*v; a[1] += pvA.y*v; a[2] += pvA.z*v; a[3] += pvA.w*v;
        a[4] += pvB.x*v; a[5] += pvB.y*v; a[6] += pvB.z*v; a[7] += pvB.w*v;
      }
      #pragma unroll
      for (int g=0;g<8;++g) cpart[o*512 + g*64 + c] = a[g];
    }
    __syncthreads();
    // ---- assemble: thread (q = t>>6, c = t&63) -> ctxT[(p*64+c)*8 + q]
    {
      int g = t>>6, c = t&63;
      float s = 0.f;
      #pragma unroll
      for (int o=0;o<8;++o) s += cpart[o*512 + g*64 + c];
      ctxT[(p*64+c)*8 + g] = s * rinv[g*8 + p*4 + (c>>4)];
    }
    // no barrier: next pass's scf writes are ordered after this pass's scf
    // reads by the post-PV barrier; next pass's cpart writes happen only
    // after its own post-score barrier (orders these cpart reads).
  }
  __syncthreads();
  // ---- wo: thread (kq = t>>7, c = t&127); K split in 4 quarters of 32
  {
    int kq = t>>7, c = t&127;
    const float* wo = A + OF_WO;
    float acc[8] = {0.f,0.f,0.f,0.f,0.f,0.f,0.f,0.f};
    #pragma unroll 4
    for (int i=kq*32; i<kq*32+32; ++i){
      float wv = wo[i*CD+c];
      float4 r0 = *(const float4*)&ctxT[i*8];
      float4 r1 = *(const float4*)&ctxT[i*8+4];
      acc[0]+=r0.x*wv; acc[1]+=r0.y*wv; acc[2]+=r0.z*wv; acc[3]+=r0.w*wv;
      acc[4]+=r1.x*wv; acc[5]+=r1.y*wv; acc[6]+=r1.z*wv; acc[7]+=r1.w*wv;
    }
    #pragma unroll
    for (int g=0;g<8;++g) cpart[kq*1024 + g*128 + c] = acc[g];
  }
  __syncthreads();
  // ---- waveized residual + LayerNorm: wave g = query g, lanes = channels
  {
    float x0 = cpart[gq*128 + lane]        + cpart[1024 + gq*128 + lane]
             + cpart[2048 + gq*128 + lane] + cpart[3072 + gq*128 + lane]
             + A[OF_BO+lane] + fres0;
    float x1 = cpart[gq*128 + lane+64]        + cpart[1024 + gq*128 + lane+64]
             + cpart[2048 + gq*128 + lane+64] + cpart[3072 + gq*128 + lane+64]
             + A[OF_BO+lane+64] + fres1;
    float s1 = x0+x1, s2 = x0*x0+x1*x1;
    #pragma unroll
    for (int o=32;o;o>>=1){ s1 += __shfl_xor(s1,o,64); s2 += __shfl_xor(s2,o,64); }
    float mean = s1*(1.f/128.f);
    float var  = s2*(1.f/128.f) - mean*mean;
    float rs = rsqrtf(var + EPSF);
    yb[(size_t)(n0+gq)*CD + lane]    = (x0-mean)*rs*A[OF_LNG+lane]    + A[OF_LNB+lane];
    yb[(size_t)(n0+gq)*CD + lane+64] = (x1-mean)*rs*A[OF_LNG+lane+64] + A[OF_LNB+lane+64];
  }
}

// ========== K10: SubMConv3d, 8 voxels/block (512 blocks), weights hoisted ==========
__global__ __launch_bounds__(256) void k10_conv(const int* idx, const int* map,
    const float* yb, const float* A, const float* wt, const int* flag, void* outv)
{
  __shared__ int sco4[8][4];
  __shared__ int jn[8][27];
  __shared__ float partial[4][8][NCD];
  int t = threadIdx.x;
  int p0 = blockIdx.x*8;
  if (t < 32) ((int*)sco4)[t] = idx[4*p0 + t];
  __syncthreads();
  if (t < 216){
    int v = t/27, nb = t - v*27;
    int kd = nb/9, kh = (nb/3)%3, kw = nb%3;
    int bb = sco4[v][0];
    int nx = sco4[v][1]+kd-1, ny = sco4[v][2]+kh-1, nz = sco4[v][3]+kw-1;
    int j = -1;
    if ((unsigned)nx < XD && (unsigned)ny < YD && (unsigned)nz < ZD)
      j = map[((bb*XD+nx)*YD+ny)*ZD+nz];
    jn[v][nb] = j;
  }
  __syncthreads();
  int w = t>>6, l = t&63;
  int og = l & 3, cg = l >> 2;
  int c0 = cg*8;
  float acc[8][5];
  #pragma unroll
  for (int v=0;v<8;++v)
    #pragma unroll
    for (int oo=0;oo<5;++oo) acc[v][oo]=0.f;
  for (int nb = w; nb < 27; nb += 4){
    const float* wbase = wt + (size_t)nb*NCD*CD + c0;
    float4 wreg[10];
    #pragma unroll
    for (int oo=0;oo<5;++oo){
      wreg[oo*2]   = *(const float4*)(wbase + (size_t)(og*5+oo)*CD);
      wreg[oo*2+1] = *(const float4*)(wbase + (size_t)(og*5+oo)*CD + 4);
    }
    #pragma unroll
    for (int v=0; v<8; ++v){
      int j = jn[v][nb];
      if (j < 0) continue;
      const float4* y4 = (const float4*)(yb + (size_t)j*CD + c0);
      float4 ya = y4[0], ybb = y4[1];
      #pragma unroll
      for (int oo=0;oo<5;++oo){
        float4 wa = wreg[oo*2], wb = wreg[oo*2+1];
        acc[v][oo] += ya.x*wa.x + ya.y*wa.y + ya.z*wa.z + ya.w*wa.w
                    + ybb.x*wb.x + ybb.y*wb.y + ybb.z*wb.z + ybb.w*wb.w;
      }
    }
  }
  #pragma unroll
  for (int v=0;v<8;++v)
    #pragma unroll
    for (int oo=0;oo<5;++oo){
      float s = acc[v][oo];
      s += __shfl_xor(s, 4, 64);
      s += __shfl_xor(s, 8, 64);
      s += __shfl_xor(s, 16, 64);
      s += __shfl_xor(s, 32, 64);
      if (cg == 0) partial[w][v][og*5+oo] = s;
    }
  __syncthreads();
  if (t < 160){
    int v = t/20, o = t - v*20;
    float s = partial[0][v][o]+partial[1][v][o]+partial[2][v][o]+partial[3][v][o]
            + A[OF_SEGB+o];
    if (*flag) ((ushort_t*)outv)[(size_t)(p0+v)*NCD + o] = f2bf(s);
    else       ((float*)outv)[(size_t)(p0+v)*NCD + o]   = s;
  }
}

// ---------------- launch ----------------
extern "C" void kernel_launch(void* const* d_in, const int* in_sizes, int n_in,
                              void* d_out, int out_size, void* d_ws, size_t ws_size,
                              hipStream_t stream) {
  const int* idx = (const int*)d_in[0];

  char* w = (char*)d_ws;
  size_t off = 0;
  #define ALLOC(name, type, count) \
    type* name = (type*)(w + off); off += (((size_t)(count)*sizeof(type)) + 255) & ~(size_t)255;
  ALLOC(flag,   int,   64)
  ALLOC(arena,  float, ARENA_N)
  ALLOC(wt,     float, 27*NCD*CD)
  ALLOC(map,    int,   MAPN)
  ALLOC(afold,  float, 192)
  ALLOC(scfold, float, 64)
  ALLOC(t1T,    float, CD*NSV)
  ALLOC(kb,     float, NSV*CD)
  ALLOC(vbuf,   float, NSV*CD)
  ALLOC(qb,     float, NVOX*CD)
  ALLOC(yb,     float, NVOX*CD)
  ALLOC(pbias_b,float, 512*256*8)
  #undef ALLOC
  (void)off; (void)ws_size; (void)n_in; (void)in_sizes; (void)out_size;

  SrcPtrs sp;
  for (int i=0;i<25;++i) sp.p[i] = d_in[i+1];

  kprep   <<<512, 512, 0, stream>>>(sp, idx, flag, arena, wt, map, afold, scfold, qb, t1T);
  k6pb    <<<1024, 256, 0, stream>>>(t1T, arena, idx, map, kb, vbuf, afold, scfold, pbias_b);
  k9_attn <<<NVOX/8, 512, 0, stream>>>(arena, idx, pbias_b, kb, vbuf, qb, d_in[1], flag, yb);
  k10_conv<<<NVOX/8, 256, 0, stream>>>(idx, map, yb, arena, wt, flag, d_out);
}

// Round 9
// 189.759 us; speedup vs baseline: 1.0980x; 1.0040x over previous
//
#include <hip/hip_runtime.h>

typedef unsigned short ushort_t;

#define NVOX 4096
#define NSV  256
#define XD   128
#define YD   128
#define ZD   16
#define CD   128
#define NCD  20
#define HD   8
#define DHD  16
#define MAPN 524288
#define EPSF 1e-5f

// ---- fp32 arena offsets (floats) ----
#define OF_FEAT 0
#define OF_CW1  524288
#define OF_CB1  540672
#define OF_CG1  540800
#define OF_CBE1 540928
#define OF_CW2  541056
#define OF_CB2  557440
#define OF_PW1  557568
#define OF_PB1  557760
#define OF_PG1  557824
#define OF_PBE1 557888
#define OF_PW2  557952
#define OF_PB2  558016
#define OF_WQ   558080
#define OF_BQ   574464
#define OF_WK   574592
#define OF_BK   590976
#define OF_WV   591104
#define OF_BV   607488
#define OF_WO   607616
#define OF_BO   624000
#define OF_LNG  624128
#define OF_LNB  624256
#define OF_SEGW 624384
#define OF_SEGB 693504
#define ARENA_N 693568
#define TOTCVT2 100053   /* arena convert, FEAT excluded (k9 reads source) */

__device__ __forceinline__ float bf2f(const ushort_t* p){
  return __uint_as_float(((unsigned)(*p)) << 16);
}
__device__ __forceinline__ ushort_t f2bf(float f){
  unsigned u = __float_as_uint(f);
  u += 0x7fffu + ((u >> 16) & 1u);
  return (ushort_t)(u >> 16);
}
__device__ __forceinline__ float unlo(unsigned u){ return __uint_as_float(u << 16); }
__device__ __forceinline__ float unhi(unsigned u){ return __uint_as_float(u & 0xffff0000u); }

struct SrcPtrs { const void* p[25]; };

// segments 1..24 of the original table (FEAT dropped); src = sp.p[s+1]
__device__ const int g_cnt2[24] = {16384,128,128,128,16384,128,192,64,64,64,64,1,
                                   16384,128,16384,128,16384,128,16384,128,128,128,0,20};
__device__ const int g_off2[24] = {OF_CW1,OF_CB1,OF_CG1,OF_CBE1,OF_CW2,OF_CB2,
                                   OF_PW1,OF_PB1,OF_PG1,OF_PBE1,OF_PW2,OF_PB2,
                                   OF_WQ,OF_BQ,OF_WK,OF_BK,OF_WV,OF_BV,OF_WO,OF_BO,
                                   OF_LNG,OF_LNB,OF_SEGW,OF_SEGB};

__device__ __forceinline__ float ldi(const void* p, int off, int fl){
  return fl ? bf2f((const ushort_t*)p + off) : ((const float*)p)[off];
}

struct SPREP {
  float frows[16][CD];     // 8 KB
  float qpart[2][16][CD];  // 16 KB
  float part[8][CD];       // 4 KB
  float cfs[CD];           // 0.5 KB
  float gpart[8][CD];      // 4 KB
};
union __align__(16) UPREP { SPREP sv; int smom[18]; };

// ========== KPREP (512 threads) ==========
__global__ __launch_bounds__(512) void kprep(SrcPtrs sp, const int* idx, int* flag,
    float* arena, float* wt, int* map, float* afold_g, float* scfold_g,
    float* qb, float* t1T)
{
  __shared__ UPREP sm;
  __shared__ int sm_flag;
  int t = threadIdx.x, b = blockIdx.x;
  if (t < 64){
    const ushort_t* f16 = (const ushort_t*)sp.p[0];
    unsigned u = f16[2*t];
    int e = (u >> 7) & 0xFF;
    int sane = (u == 0 || (e >= 90 && e <= 150)) ? 1 : 0;
    unsigned long long bl = __ballot(sane);
    if (t == 0) sm_flag = (__popcll(bl) >= 48) ? 1 : 0;
  }
  __syncthreads();
  const int fl = sm_flag;

  if (b < 255){
    int gid = b*512 + t;
    const int GS = 255*512;
    if (gid == 0) *flag = fl;
    for (int k=gid; k<MAPN; k+=GS) map[k] = -1;
    for (int el=gid; el<TOTCVT2; el+=GS){
      int s=0, rem=el;
      while (rem >= g_cnt2[s]){ rem -= g_cnt2[s]; ++s; }
      arena[g_off2[s]+rem] = ldi(sp.p[s+1], rem, fl);
    }
    for (int k=gid; k<27*NCD*CD; k+=GS){
      int nb = k/(NCD*CD); int rem = k - nb*(NCD*CD); int o = rem/CD, i = rem - o*CD;
      wt[k] = ldi(sp.p[23], nb*(CD*NCD) + i*NCD + o, fl);
    }
  } else if (b < 511){
    int sv = b - 255;
    int rb = sv*16;
    if (fl){
      const uint2* fsrc = (const uint2*)((const ushort_t*)sp.p[0] + (size_t)rb*CD);
      uint2 u = fsrc[t];
      float* dst = &sm.sv.frows[t>>5][(t&31)*4];
      dst[0]=unlo(u.x); dst[1]=unhi(u.x); dst[2]=unlo(u.y); dst[3]=unhi(u.y);
    } else {
      const float4* fsrc = (const float4*)((const float*)sp.p[0] + (size_t)rb*CD);
      ((float4*)sm.sv.frows)[t] = fsrc[t];
    }
    __syncthreads();
    // ---- q-proj: thread = (c8:16, row:16, khalf:2)
    {
      int c8 = (t&15)*8, r = (t>>4)&15, kh = t>>8;
      int i0 = kh*64;
      float acc[8] = {0.f,0.f,0.f,0.f,0.f,0.f,0.f,0.f};
      if (fl){
        const ushort_t* wqp = (const ushort_t*)sp.p[13];
        #pragma unroll 4
        for (int i=i0; i<i0+64; ++i){
          uint4 w4 = *(const uint4*)(wqp + (size_t)i*CD + c8);
          float fr = sm.sv.frows[r][i];
          acc[0] += unlo(w4.x)*fr; acc[1] += unhi(w4.x)*fr;
          acc[2] += unlo(w4.y)*fr; acc[3] += unhi(w4.y)*fr;
          acc[4] += unlo(w4.z)*fr; acc[5] += unhi(w4.z)*fr;
          acc[6] += unlo(w4.w)*fr; acc[7] += unhi(w4.w)*fr;
        }
      } else {
        const float* wqp = (const float*)sp.p[13];
        #pragma unroll 4
        for (int i=i0; i<i0+64; ++i){
          float4 wa = *(const float4*)(wqp + (size_t)i*CD + c8);
          float4 wb = *(const float4*)(wqp + (size_t)i*CD + c8 + 4);
          float fr = sm.sv.frows[r][i];
          acc[0]+=wa.x*fr; acc[1]+=wa.y*fr; acc[2]+=wa.z*fr; acc[3]+=wa.w*fr;
          acc[4]+=wb.x*fr; acc[5]+=wb.y*fr; acc[6]+=wb.z*fr; acc[7]+=wb.w*fr;
        }
      }
      #pragma unroll
      for (int j=0;j<8;++j) sm.sv.qpart[kh][r][c8+j] = acc[j];
    }
    __syncthreads();
    for (int e = t; e < 16*CD; e += 512){
      int r = e>>7, c = e&127;
      qb[(size_t)(rb+r)*CD + c] = sm.sv.qpart[0][r][c] + sm.sv.qpart[1][r][c]
                                + ldi(sp.p[14], c, fl);
    }
    // ---- segment softmax-sum: 8 waves x 2 rows
    {
      int w = t>>6, l = t&63;
      float a0 = 0.f, a1 = 0.f;
      #pragma unroll
      for (int k=0;k<2;++k){
        int r = w*2 + k;
        float f0 = sm.sv.frows[r][l];
        float f1 = sm.sv.frows[r][l+64];
        float m = fmaxf(f0,f1);
        #pragma unroll
        for (int o=32;o;o>>=1) m = fmaxf(m, __shfl_xor(m,o,64));
        float e0 = __expf(f0-m), e1 = __expf(f1-m);
        float ssum = e0+e1;
        #pragma unroll
        for (int o=32;o;o>>=1) ssum += __shfl_xor(ssum,o,64);
        float inv = 1.f/ssum;
        a0 += e0*inv; a1 += e1*inv;
      }
      sm.sv.part[w][l] = a0; sm.sv.part[w][l+64] = a1;
    }
    __syncthreads();
    if (t < CD){
      float s = 0.f;
      #pragma unroll
      for (int w=0;w<8;++w) s += sm.sv.part[w][t];
      sm.sv.cfs[t] = s;
    }
    __syncthreads();
    // ---- GEMV1: thread = (c2:64, kg:8)
    {
      int c2 = (t&63)*2, kg = t>>6;
      int i0 = kg*16;
      float a0 = 0.f, a1 = 0.f;
      if (fl){
        const ushort_t* W = (const ushort_t*)sp.p[1];
        #pragma unroll 4
        for (int i=i0; i<i0+16; ++i){
          unsigned w = *(const unsigned*)(W + (size_t)i*CD + c2);
          float cfv = sm.sv.cfs[i];
          a0 += unlo(w)*cfv; a1 += unhi(w)*cfv;
        }
      } else {
        const float* W = (const float*)sp.p[1];
        #pragma unroll 4
        for (int i=i0; i<i0+16; ++i){
          float2 w = *(const float2*)(W + (size_t)i*CD + c2);
          float cfv = sm.sv.cfs[i];
          a0 += w.x*cfv; a1 += w.y*cfv;
        }
      }
      sm.sv.gpart[kg][c2] = a0; sm.sv.gpart[kg][c2+1] = a1;
    }
    __syncthreads();
    if (t < CD){
      float s = 0.f;
      #pragma unroll
      for (int kg=0;kg<8;++kg) s += sm.sv.gpart[kg][t];
      t1T[(size_t)t*NSV + sv] = s + ldi(sp.p[2], t, fl);
    }
  } else {
    // ---- b == 511: moments + BN fold (wave-reduced, no per-lane LDS atomic storms)
    if (t < 18) sm.smom[t] = 0;
    __syncthreads();
    {
      // voxel moments
      int sacc[9] = {0,0,0,0,0,0,0,0,0};
      for (int v = t; v < NVOX; v += 512){
        int4 q = ((const int4*)idx)[v];
        sacc[0]+=q.y; sacc[1]+=q.z; sacc[2]+=q.w;
        sacc[3]+=q.y*q.y; sacc[4]+=q.z*q.z; sacc[5]+=q.w*q.w;
        sacc[6]+=q.y*q.z; sacc[7]+=q.y*q.w; sacc[8]+=q.z*q.w;
      }
      // supervoxel (cell) moments
      int um[9] = {0,0,0,0,0,0,0,0,0};
      if (t < 256){
        int4 q = ((const int4*)idx)[t*16];
        int gx=q.y>>2, gy=q.z>>2, gz=q.w>>2;
        um[0]=gx; um[1]=gy; um[2]=gz;
        um[3]=gx*gx; um[4]=gy*gy; um[5]=gz*gz;
        um[6]=gx*gy; um[7]=gx*gz; um[8]=gy*gz;
      }
      // 64-lane shuffle tree per moment, one atomic per wave per moment
      int lane = t & 63;
      #pragma unroll
      for (int i=0;i<9;++i){
        int s = sacc[i];
        int u = um[i];
        #pragma unroll
        for (int o=32;o;o>>=1){
          s += __shfl_xor(s, o, 64);
          u += __shfl_xor(u, o, 64);
        }
        if (lane == 0){
          if (s) atomicAdd(&sm.smom[9+i], s);
          if (u) atomicAdd(&sm.smom[i], u);
        }
      }
    }
    __syncthreads();
    if (t < 64){
      int* smom = sm.smom;
      double U1[3]={(double)smom[0],(double)smom[1],(double)smom[2]};
      double S1[3]={(double)smom[9],(double)smom[10],(double)smom[11]};
      double Uxx[3][3], Sxx[3][3];
      Uxx[0][0]=smom[3]; Uxx[1][1]=smom[4]; Uxx[2][2]=smom[5];
      Uxx[0][1]=Uxx[1][0]=smom[6]; Uxx[0][2]=Uxx[2][0]=smom[7]; Uxx[1][2]=Uxx[2][1]=smom[8];
      Sxx[0][0]=smom[12]; Sxx[1][1]=smom[13]; Sxx[2][2]=smom[14];
      Sxx[0][1]=Sxx[1][0]=smom[15]; Sxx[0][2]=Sxx[2][0]=smom[16]; Sxx[1][2]=Sxx[2][1]=smom[17];
      double M1[3], M2[3][3];
      for (int a=0;a<3;++a) M1[a] = 256.0*S1[a] - 4096.0*U1[a];
      for (int a=0;a<3;++a)
        for (int b2=0;b2<3;++b2)
          M2[a][b2] = 256.0*Sxx[a][b2] - S1[a]*U1[b2] - S1[b2]*U1[a] + 4096.0*Uxx[a][b2];
      double wv_[3]={(double)ldi(sp.p[7],t,fl),(double)ldi(sp.p[7],64+t,fl),(double)ldi(sp.p[7],128+t,fl)};
      double bj=(double)ldi(sp.p[8],t,fl), gj=(double)ldi(sp.p[9],t,fl), bej=(double)ldi(sp.p[10],t,fl);
      double Mw=0.0, wMw=0.0;
      for (int a=0;a<3;++a){
        Mw += M1[a]*wv_[a];
        for (int b2=0;b2<3;++b2) wMw += wv_[a]*M2[a][b2]*wv_[b2];
      }
      const double NM = 1048576.0;
      double mean = Mw/NM + bj;
      double Ey2  = wMw/NM + 2.0*bj*Mw/NM + bj*bj;
      double var  = Ey2 - mean*mean;
      double scale = gj / sqrt(var + 1e-5);
      afold_g[t]      = (float)(wv_[0]*scale);
      afold_g[64+t]   = (float)(wv_[1]*scale);
      afold_g[128+t]  = (float)(wv_[2]*scale);
      scfold_g[t]     = (float)(bj*scale + bej - mean*scale);
    }
  }
}

// ========== K6PB: 1024 blocks. b<512: pbias table (8 queries/block).
//            b in [512,1024): k6 GEMVs (role = (b-512)>>8: 0=k, 1=v). ==========
__global__ __launch_bounds__(256) void k6pb(const float* t1T, const float* A,
    const int* idx, int* map, float* kb, float* vb,
    const float* afold_g, const float* scfold_g, float* pbias_b)
{
  __shared__ float saf[3][64];
  __shared__ float ssc[64];
  __shared__ float w2s[64];
  __shared__ __align__(16) float e4q[64][8];
  __shared__ float xs[8], ys[8], zs[8];
  __shared__ float row[CD];
  __shared__ float cpar[2][CD];
  __shared__ float hrow[CD];
  int t = threadIdx.x, b = blockIdx.x;
  if (b < 512){
    // ---- pbias: hoisted 64-iter MLP; layout pbias_b[(b*256+s)*8 + qi]
    if (t < 64){
      saf[0][t] = afold_g[t]; saf[1][t] = afold_g[64+t]; saf[2][t] = afold_g[128+t];
      ssc[t] = scfold_g[t]; w2s[t] = A[OF_PW2+t];
    } else if (t < 72){
      int qi = t - 64;
      int4 q = ((const int4*)idx)[b*8 + qi];
      xs[qi] = (float)q.y; ys[qi] = (float)q.z; zs[qi] = (float)q.w;
    }
    __syncthreads();
    for (int e = t; e < 512; e += 256){
      int j = e & 63, qi = e >> 6;
      e4q[j][qi] = saf[0][j]*xs[qi] + saf[1][j]*ys[qi] + saf[2][j]*zs[qi];
    }
    __syncthreads();
    int4 q0 = ((const int4*)idx)[t*16];
    float ux = (float)(q0.y>>2), uy = (float)(q0.z>>2), uz = (float)(q0.w>>2);
    float pb2 = A[OF_PB2];
    float pbv[8];
    #pragma unroll
    for (int i=0;i<8;++i) pbv[i] = pb2;
    #pragma unroll 2
    for (int j=0;j<64;++j){
      float dj = ssc[j] - (saf[0][j]*ux + saf[1][j]*uy + saf[2][j]*uz);
      float wj = w2s[j];
      float4 e0 = *(const float4*)&e4q[j][0];
      float4 e1 = *(const float4*)&e4q[j][4];
      pbv[0] += fmaxf(e0.x+dj,0.f)*wj; pbv[1] += fmaxf(e0.y+dj,0.f)*wj;
      pbv[2] += fmaxf(e0.z+dj,0.f)*wj; pbv[3] += fmaxf(e0.w+dj,0.f)*wj;
      pbv[4] += fmaxf(e1.x+dj,0.f)*wj; pbv[5] += fmaxf(e1.y+dj,0.f)*wj;
      pbv[6] += fmaxf(e1.z+dj,0.f)*wj; pbv[7] += fmaxf(e1.w+dj,0.f)*wj;
    }
    float* dst = pbias_b + ((size_t)b*256 + t)*8;
    *(float4*)dst       = make_float4(pbv[0],pbv[1],pbv[2],pbv[3]);
    *(float4*)(dst + 4) = make_float4(pbv[4],pbv[5],pbv[6],pbv[7]);
    return;
  }
  // ---- k6: BN-fold + relu + cw2 + {wk|wv} projection for supervoxel s
  int role = (b - 512) >> 8, s = (b - 512) & 255;
  if (role == 0 && t >= 128 && t < 144){
    int v = s*16 + (t-128);
    int4 q = ((const int4*)idx)[v];
    map[((q.x*XD + q.y)*YD + q.z)*ZD + q.w] = v;
  }
  if (t < CD){
    const float4* col = (const float4*)(t1T + (size_t)t*NSV);
    float sum=0.f, sq=0.f;
    #pragma unroll 8
    for (int i=0;i<NSV/4;++i){
      float4 v = col[i];
      sum += v.x+v.y+v.z+v.w;
      sq  += v.x*v.x+v.y*v.y+v.z*v.z+v.w*v.w;
    }
    float mean = sum*(1.f/256.f);
    float var  = sq*(1.f/256.f) - mean*mean;
    float scv = A[OF_CG1+t]*rsqrtf(var+EPSF);
    float shv = A[OF_CBE1+t] - mean*scv;
    row[t] = fmaxf(t1T[(size_t)t*NSV + s]*scv + shv, 0.f);
  }
  __syncthreads();
  int c = t&127, half = t>>7;
  {
    const float* W = A + OF_CW2;
    float acc = 0.f;
    #pragma unroll 8
    for (int i=half*64;i<half*64+64;++i) acc += row[i]*W[i*CD+c];
    cpar[half][c] = acc;
  }
  __syncthreads();
  if (t < CD) hrow[t] = cpar[0][t]+cpar[1][t]+A[OF_CB2+t];
  __syncthreads();
  {
    const float* W = role ? (A+OF_WV) : (A+OF_WK);
    float acc = 0.f;
    #pragma unroll 8
    for (int i=half*64;i<half*64+64;++i) acc += hrow[i]*W[i*CD+c];
    cpar[half][c] = acc;
  }
  __syncthreads();
  if (t < CD){
    float v = cpar[0][t]+cpar[1][t] + (role ? A[OF_BV+t] : A[OF_BK+t]);
    if (role) vb[(size_t)s*CD+t] = v; else kb[(size_t)s*CD+t] = v;
  }
}

// ========== K9 v8: Q=8, 512 threads; waveized residual/LN tail ==========
#define CGRP(row,hh) (((hh) + ((row)>>1)) & 3)

__global__ __launch_bounds__(512, 4) void k9_attn(
    const float* A, const int* idx, const float* pbias_b,
    const float* kb, const float* vb, const float* qb,
    const void* featsrc, const int* flag, float* yb)
{
  __shared__ __align__(16) float q8s[8][CD];       // 4 KB [q][c]
  __shared__ __align__(16) float scf[NSV][32];     // 32 KB swizzled probs (4h x 8q)
  __shared__ __align__(16) float ctxT[CD*8];       // 4 KB [c][q] stride 8
  __shared__ __align__(16) float cpart[4096];      // 16 KB (PV: [o][q][c64]; wo: [kq][q][c128])
  __shared__ float rinv[64];                       // [q*8 + h]
  int t = threadIdx.x;
  int n0 = blockIdx.x*8;
  const int fl = *flag;
  if (t < 256) ((float4*)q8s)[t] = ((const float4*)(qb + (size_t)n0*CD))[t];
  int ts = t & 255, hp = t >> 8;
  // pbias for (sv=ts, all 8 queries): two aligned float4s; layout matches kpb
  const float* pbp = pbias_b + ((size_t)blockIdx.x*256 + ts)*8;
  float4 pbq0 = *(const float4*)pbp;
  float4 pbq1 = *(const float4*)(pbp + 4);
  float pb[8] = {pbq0.x,pbq0.y,pbq0.z,pbq0.w, pbq1.x,pbq1.y,pbq1.z,pbq1.w};
  // early-issue residual feature loads for the tail (wave g, lanes = channels)
  int gq = t>>6, lane = t&63;
  float fres0, fres1;
  if (fl){
    fres0 = bf2f((const ushort_t*)featsrc + (size_t)(n0+gq)*CD + lane);
    fres1 = bf2f((const ushort_t*)featsrc + (size_t)(n0+gq)*CD + lane + 64);
  } else {
    fres0 = ((const float*)featsrc)[(size_t)(n0+gq)*CD + lane];
    fres1 = ((const float*)featsrc)[(size_t)(n0+gq)*CD + lane + 64];
  }
  __syncthreads();
  const float4* krow = (const float4*)(kb + (size_t)ts*CD);
  #pragma unroll
  for (int p=0;p<2;++p){
    // ---- scores + exp: thread (ts, hp) handles hh = hp*2, hp*2+1
    {
      #pragma unroll
      for (int u=0; u<2; ++u){
        int hh = hp*2 + u;
        int h = p*4 + hh;
        float4 k0 = krow[h*4+0], k1 = krow[h*4+1], k2 = krow[h*4+2], k3 = krow[h*4+3];
        float pr[8];
        #pragma unroll
        for (int g=0; g<8; ++g){
          const float4* qg4 = (const float4*)&q8s[g][h*DHD];
          float4 qa = qg4[0], qbv = qg4[1], qc = qg4[2], qd = qg4[3];
          float dot = qa.x*k0.x + qa.y*k0.y + qa.z*k0.z + qa.w*k0.w
                    + qbv.x*k1.x + qbv.y*k1.y + qbv.z*k1.z + qbv.w*k1.w
                    + qc.x*k2.x + qc.y*k2.y + qc.z*k2.z + qc.w*k2.w
                    + qd.x*k3.x + qd.y*k3.y + qd.z*k3.z + qd.w*k3.w;
          pr[g] = __expf(dot*0.25f + pb[g]);
        }
        int c4a = (hh*2+0) ^ (ts&7);
        int c4b = (hh*2+1) ^ (ts&7);
        *(float4*)&scf[ts][c4a*4] = make_float4(pr[0],pr[1],pr[2],pr[3]);
        *(float4*)&scf[ts][c4b*4] = make_float4(pr[4],pr[5],pr[6],pr[7]);
      }
    }
    __syncthreads();
    // ---- denominators: wave w = query w (8 waves), 4 heads each
    {
      int w = t>>6;
      int qg = w>>2, j = w&3;
      #pragma unroll
      for (int hh=0; hh<4; ++hh){
        int slot = hh*2 + qg;
        float s0 = 0.f;
        #pragma unroll
        for (int k=0;k<4;++k){
          int r = lane + 64*k;
          s0 += scf[r][(slot ^ (r&7))*4 + j];
        }
        #pragma unroll
        for (int o=32;o;o>>=1) s0 += __shfl_xor(s0,o,64);
        if (lane==0) rinv[w*8 + p*4 + hh] = 1.f/s0;
      }
    }
    // ---- PV: thread (octant o = t>>6, channel c = t&63) of pass channels
    {
      int o = t>>6, c = t&63, hh = c>>4;
      const float* vcol = vb + p*64 + c;
      float a[8] = {0.f,0.f,0.f,0.f,0.f,0.f,0.f,0.f};
      int sA = hh*2+0, sB = hh*2+1;
      #pragma unroll 4
      for (int s=o*32; s<o*32+32; ++s){
        float v = vcol[(size_t)s*CD];
        float4 pvA = *(const float4*)&scf[s][(sA ^ (s&7))*4];
        float4 pvB = *(const float4*)&scf[s][(sB ^ (s&7))*4];
        a[0] += pvA.x*v; a[1] += pvA.y*v; a[2] += pvA.z*v; a[3] += pvA.w*v;
        a[4] += pvB.x*v; a[5] += pvB.y*v; a[6] += pvB.z*v; a[7] += pvB.w*v;
      }
      #pragma unroll
      for (int g=0;g<8;++g) cpart[o*512 + g*64 + c] = a[g];
    }
    __syncthreads();
    // ---- assemble: thread (q = t>>6, c = t&63) -> ctxT[(p*64+c)*8 + q]
    {
      int g = t>>6, c = t&63;
      float s = 0.f;
      #pragma unroll
      for (int o=0;o<8;++o) s += cpart[o*512 + g*64 + c];
      ctxT[(p*64+c)*8 + g] = s * rinv[g*8 + p*4 + (c>>4)];
    }
    // no barrier: next pass's scf writes are ordered after this pass's scf
    // reads by the post-PV barrier; next pass's cpart writes happen only
    // after its own post-score barrier (orders these cpart reads).
  }
  __syncthreads();
  // ---- wo: thread (kq = t>>7, c = t&127); K split in 4 quarters of 32
  {
    int kq = t>>7, c = t&127;
    const float* wo = A + OF_WO;
    float acc[8] = {0.f,0.f,0.f,0.f,0.f,0.f,0.f,0.f};
    #pragma unroll 4
    for (int i=kq*32; i<kq*32+32; ++i){
      float wv = wo[i*CD+c];
      float4 r0 = *(const float4*)&ctxT[i*8];
      float4 r1 = *(const float4*)&ctxT[i*8+4];
      acc[0]+=r0.x*wv; acc[1]+=r0.y*wv; acc[2]+=r0.z*wv; acc[3]+=r0.w*wv;
      acc[4]+=r1.x*wv; acc[5]+=r1.y*wv; acc[6]+=r1.z*wv; acc[7]+=r1.w*wv;
    }
    #pragma unroll
    for (int g=0;g<8;++g) cpart[kq*1024 + g*128 + c] = acc[g];
  }
  __syncthreads();
  // ---- waveized residual + LayerNorm: wave g = query g, lanes = channels
  {
    float x0 = cpart[gq*128 + lane]        + cpart[1024 + gq*128 + lane]
             + cpart[2048 + gq*128 + lane] + cpart[3072 + gq*128 + lane]
             + A[OF_BO+lane] + fres0;
    float x1 = cpart[gq*128 + lane+64]        + cpart[1024 + gq*128 + lane+64]
             + cpart[2048 + gq*128 + lane+64] + cpart[3072 + gq*128 + lane+64]
             + A[OF_BO+lane+64] + fres1;
    float s1 = x0+x1, s2 = x0*x0+x1*x1;
    #pragma unroll
    for (int o=32;o;o>>=1){ s1 += __shfl_xor(s1,o,64); s2 += __shfl_xor(s2,o,64); }
    float mean = s1*(1.f/128.f);
    float var  = s2*(1.f/128.f) - mean*mean;
    float rs = rsqrtf(var + EPSF);
    yb[(size_t)(n0+gq)*CD + lane]    = (x0-mean)*rs*A[OF_LNG+lane]    + A[OF_LNB+lane];
    yb[(size_t)(n0+gq)*CD + lane+64] = (x1-mean)*rs*A[OF_LNG+lane+64] + A[OF_LNB+lane+64];
  }
}

// ========== K10 v2: SubMConv3d, 8 voxels/block, 512 threads (8 waves) ==========
// k10 is a gather of L2-resident data (~200-cyc latency) at only 8 waves/CU
// (25% occupancy) -- the thinnest latency hiding in the pipeline. Per-block
// weight traffic is wave-count-invariant (each nb's 10 KB slice loads once
// per block), so 512 threads double resident waves to 16/CU with zero extra
// L2 traffic: wave w handles nb = w, w+8, w+16(, w+24).
__global__ __launch_bounds__(512) void k10_conv(const int* idx, const int* map,
    const float* yb, const float* A, const float* wt, const int* flag, void* outv)
{
  __shared__ int sco4[8][4];
  __shared__ int jn[8][27];
  __shared__ float partial[8][8][NCD];   // 5 KB
  int t = threadIdx.x;
  int p0 = blockIdx.x*8;
  if (t < 32) ((int*)sco4)[t] = idx[4*p0 + t];
  __syncthreads();
  if (t < 216){
    int v = t/27, nb = t - v*27;
    int kd = nb/9, kh = (nb/3)%3, kw = nb%3;
    int bb = sco4[v][0];
    int nx = sco4[v][1]+kd-1, ny = sco4[v][2]+kh-1, nz = sco4[v][3]+kw-1;
    int j = -1;
    if ((unsigned)nx < XD && (unsigned)ny < YD && (unsigned)nz < ZD)
      j = map[((bb*XD+nx)*YD+ny)*ZD+nz];
    jn[v][nb] = j;
  }
  __syncthreads();
  int w = t>>6, l = t&63;
  int og = l & 3, cg = l >> 2;
  int c0 = cg*8;
  float acc[8][5];
  #pragma unroll
  for (int v=0;v<8;++v)
    #pragma unroll
    for (int oo=0;oo<5;++oo) acc[v][oo]=0.f;
  for (int nb = w; nb < 27; nb += 8){
    const float* wbase = wt + (size_t)nb*NCD*CD + c0;
    float4 wreg[10];
    #pragma unroll
    for (int oo=0;oo<5;++oo){
      wreg[oo*2]   = *(const float4*)(wbase + (size_t)(og*5+oo)*CD);
      wreg[oo*2+1] = *(const float4*)(wbase + (size_t)(og*5+oo)*CD + 4);
    }
    #pragma unroll
    for (int v=0; v<8; ++v){
      int j = jn[v][nb];
      if (j < 0) continue;
      const float4* y4 = (const float4*)(yb + (size_t)j*CD + c0);
      float4 ya = y4[0], ybb = y4[1];
      #pragma unroll
      for (int oo=0;oo<5;++oo){
        float4 wa = wreg[oo*2], wb = wreg[oo*2+1];
        acc[v][oo] += ya.x*wa.x + ya.y*wa.y + ya.z*wa.z + ya.w*wa.w
                    + ybb.x*wb.x + ybb.y*wb.y + ybb.z*wb.z + ybb.w*wb.w;
      }
    }
  }
  #pragma unroll
  for (int v=0;v<8;++v)
    #pragma unroll
    for (int oo=0;oo<5;++oo){
      float s = acc[v][oo];
      s += __shfl_xor(s, 4, 64);
      s += __shfl_xor(s, 8, 64);
      s += __shfl_xor(s, 16, 64);
      s += __shfl_xor(s, 32, 64);
      if (cg == 0) partial[w][v][og*5+oo] = s;
    }
  __syncthreads();
  if (t < 160){
    int v = t/20, o = t - v*20;
    float s = partial[0][v][o]+partial[1][v][o]+partial[2][v][o]+partial[3][v][o]
            + partial[4][v][o]+partial[5][v][o]+partial[6][v][o]+partial[7][v][o]
            + A[OF_SEGB+o];
    if (*flag) ((ushort_t*)outv)[(size_t)(p0+v)*NCD + o] = f2bf(s);
    else       ((float*)outv)[(size_t)(p0+v)*NCD + o]   = s;
  }
}

// ---------------- launch ----------------
extern "C" void kernel_launch(void* const* d_in, const int* in_sizes, int n_in,
                              void* d_out, int out_size, void* d_ws, size_t ws_size,
                              hipStream_t stream) {
  const int* idx = (const int*)d_in[0];

  char* w = (char*)d_ws;
  size_t off = 0;
  #define ALLOC(name, type, count) \
    type* name = (type*)(w + off); off += (((size_t)(count)*sizeof(type)) + 255) & ~(size_t)255;
  ALLOC(flag,   int,   64)
  ALLOC(arena,  float, ARENA_N)
  ALLOC(wt,     float, 27*NCD*CD)
  ALLOC(map,    int,   MAPN)
  ALLOC(afold,  float, 192)
  ALLOC(scfold, float, 64)
  ALLOC(t1T,    float, CD*NSV)
  ALLOC(kb,     float, NSV*CD)
  ALLOC(vbuf,   float, NSV*CD)
  ALLOC(qb,     float, NVOX*CD)
  ALLOC(yb,     float, NVOX*CD)
  ALLOC(pbias_b,float, 512*256*8)
  #undef ALLOC
  (void)off; (void)ws_size; (void)n_in; (void)in_sizes; (void)out_size;

  SrcPtrs sp;
  for (int i=0;i<25;++i) sp.p[i] = d_in[i+1];

  kprep   <<<512, 512, 0, stream>>>(sp, idx, flag, arena, wt, map, afold, scfold, qb, t1T);
  k6pb    <<<1024, 256, 0, stream>>>(t1T, arena, idx, map, kb, vbuf, afold, scfold, pbias_b);
  k9_attn <<<NVOX/8, 512, 0, stream>>>(arena, idx, pbias_b, kb, vbuf, qb, d_in[1], flag, yb);
  k10_conv<<<NVOX/8, 512, 0, stream>>>(idx, map, yb, arena, wt, flag, d_out);
}

// Round 10
// 189.328 us; speedup vs baseline: 1.1005x; 1.0023x over previous
//
#include <hip/hip_runtime.h>

typedef unsigned short ushort_t;

#define NVOX 4096
#define NSV  256
#define XD   128
#define YD   128
#define ZD   16
#define CD   128
#define NCD  20
#define HD   8
#define DHD  16
#define MAPN 524288
#define EPSF 1e-5f

// ---- fp32 arena offsets (floats) ----
#define OF_FEAT 0
#define OF_CW1  524288
#define OF_CB1  540672
#define OF_CG1  540800
#define OF_CBE1 540928
#define OF_CW2  541056
#define OF_CB2  557440
#define OF_PW1  557568
#define OF_PB1  557760
#define OF_PG1  557824
#define OF_PBE1 557888
#define OF_PW2  557952
#define OF_PB2  558016
#define OF_WQ   558080
#define OF_BQ   574464
#define OF_WK   574592
#define OF_BK   590976
#define OF_WV   591104
#define OF_BV   607488
#define OF_WO   607616
#define OF_BO   624000
#define OF_LNG  624128
#define OF_LNB  624256
#define OF_SEGW 624384
#define OF_SEGB 693504
#define ARENA_N 693568
#define TOTCVT2 100053   /* arena convert, FEAT excluded (k9 reads source) */

__device__ __forceinline__ float bf2f(const ushort_t* p){
  return __uint_as_float(((unsigned)(*p)) << 16);
}
__device__ __forceinline__ ushort_t f2bf(float f){
  unsigned u = __float_as_uint(f);
  u += 0x7fffu + ((u >> 16) & 1u);
  return (ushort_t)(u >> 16);
}
__device__ __forceinline__ float unlo(unsigned u){ return __uint_as_float(u << 16); }
__device__ __forceinline__ float unhi(unsigned u){ return __uint_as_float(u & 0xffff0000u); }

struct SrcPtrs { const void* p[25]; };

// segments 1..24 of the original table (FEAT dropped); src = sp.p[s+1]
__device__ const int g_cnt2[24] = {16384,128,128,128,16384,128,192,64,64,64,64,1,
                                   16384,128,16384,128,16384,128,16384,128,128,128,0,20};
__device__ const int g_off2[24] = {OF_CW1,OF_CB1,OF_CG1,OF_CBE1,OF_CW2,OF_CB2,
                                   OF_PW1,OF_PB1,OF_PG1,OF_PBE1,OF_PW2,OF_PB2,
                                   OF_WQ,OF_BQ,OF_WK,OF_BK,OF_WV,OF_BV,OF_WO,OF_BO,
                                   OF_LNG,OF_LNB,OF_SEGW,OF_SEGB};

__device__ __forceinline__ float ldi(const void* p, int off, int fl){
  return fl ? bf2f((const ushort_t*)p + off) : ((const float*)p)[off];
}

struct SPREP {
  float frows[16][CD];     // 8 KB
  float qpart[2][16][CD];  // 16 KB
  float part[8][CD];       // 4 KB
  float cfs[CD];           // 0.5 KB
  float gpart[8][CD];      // 4 KB
};
union __align__(16) UPREP { SPREP sv; int smom[18]; };

// ========== KPREP (512 threads) ==========
// Supervoxel blocks additionally accumulate per-channel BN stats of t1T
// (sum, sumsq) into tstats[0..127] / tstats[128..255] via fp32 atomics
// (256 contenders/address) so k6 no longer re-reads all of t1T per block.
__global__ __launch_bounds__(512) void kprep(SrcPtrs sp, const int* idx, int* flag,
    float* arena, float* wt, int* map, float* afold_g, float* scfold_g,
    float* qb, float* t1T, float* tstats)
{
  __shared__ UPREP sm;
  __shared__ int sm_flag;
  int t = threadIdx.x, b = blockIdx.x;
  if (t < 64){
    const ushort_t* f16 = (const ushort_t*)sp.p[0];
    unsigned u = f16[2*t];
    int e = (u >> 7) & 0xFF;
    int sane = (u == 0 || (e >= 90 && e <= 150)) ? 1 : 0;
    unsigned long long bl = __ballot(sane);
    if (t == 0) sm_flag = (__popcll(bl) >= 48) ? 1 : 0;
  }
  __syncthreads();
  const int fl = sm_flag;

  if (b < 255){
    int gid = b*512 + t;
    const int GS = 255*512;
    if (gid == 0) *flag = fl;
    for (int k=gid; k<MAPN; k+=GS) map[k] = -1;
    for (int el=gid; el<TOTCVT2; el+=GS){
      int s=0, rem=el;
      while (rem >= g_cnt2[s]){ rem -= g_cnt2[s]; ++s; }
      arena[g_off2[s]+rem] = ldi(sp.p[s+1], rem, fl);
    }
    for (int k=gid; k<27*NCD*CD; k+=GS){
      int nb = k/(NCD*CD); int rem = k - nb*(NCD*CD); int o = rem/CD, i = rem - o*CD;
      wt[k] = ldi(sp.p[23], nb*(CD*NCD) + i*NCD + o, fl);
    }
  } else if (b < 511){
    int sv = b - 255;
    int rb = sv*16;
    if (fl){
      const uint2* fsrc = (const uint2*)((const ushort_t*)sp.p[0] + (size_t)rb*CD);
      uint2 u = fsrc[t];
      float* dst = &sm.sv.frows[t>>5][(t&31)*4];
      dst[0]=unlo(u.x); dst[1]=unhi(u.x); dst[2]=unlo(u.y); dst[3]=unhi(u.y);
    } else {
      const float4* fsrc = (const float4*)((const float*)sp.p[0] + (size_t)rb*CD);
      ((float4*)sm.sv.frows)[t] = fsrc[t];
    }
    __syncthreads();
    // ---- q-proj: thread = (c8:16, row:16, khalf:2)
    {
      int c8 = (t&15)*8, r = (t>>4)&15, kh = t>>8;
      int i0 = kh*64;
      float acc[8] = {0.f,0.f,0.f,0.f,0.f,0.f,0.f,0.f};
      if (fl){
        const ushort_t* wqp = (const ushort_t*)sp.p[13];
        #pragma unroll 4
        for (int i=i0; i<i0+64; ++i){
          uint4 w4 = *(const uint4*)(wqp + (size_t)i*CD + c8);
          float fr = sm.sv.frows[r][i];
          acc[0] += unlo(w4.x)*fr; acc[1] += unhi(w4.x)*fr;
          acc[2] += unlo(w4.y)*fr; acc[3] += unhi(w4.y)*fr;
          acc[4] += unlo(w4.z)*fr; acc[5] += unhi(w4.z)*fr;
          acc[6] += unlo(w4.w)*fr; acc[7] += unhi(w4.w)*fr;
        }
      } else {
        const float* wqp = (const float*)sp.p[13];
        #pragma unroll 4
        for (int i=i0; i<i0+64; ++i){
          float4 wa = *(const float4*)(wqp + (size_t)i*CD + c8);
          float4 wb = *(const float4*)(wqp + (size_t)i*CD + c8 + 4);
          float fr = sm.sv.frows[r][i];
          acc[0]+=wa.x*fr; acc[1]+=wa.y*fr; acc[2]+=wa.z*fr; acc[3]+=wa.w*fr;
          acc[4]+=wb.x*fr; acc[5]+=wb.y*fr; acc[6]+=wb.z*fr; acc[7]+=wb.w*fr;
        }
      }
      #pragma unroll
      for (int j=0;j<8;++j) sm.sv.qpart[kh][r][c8+j] = acc[j];
    }
    __syncthreads();
    for (int e = t; e < 16*CD; e += 512){
      int r = e>>7, c = e&127;
      qb[(size_t)(rb+r)*CD + c] = sm.sv.qpart[0][r][c] + sm.sv.qpart[1][r][c]
                                + ldi(sp.p[14], c, fl);
    }
    // ---- segment softmax-sum: 8 waves x 2 rows
    {
      int w = t>>6, l = t&63;
      float a0 = 0.f, a1 = 0.f;
      #pragma unroll
      for (int k=0;k<2;++k){
        int r = w*2 + k;
        float f0 = sm.sv.frows[r][l];
        float f1 = sm.sv.frows[r][l+64];
        float m = fmaxf(f0,f1);
        #pragma unroll
        for (int o=32;o;o>>=1) m = fmaxf(m, __shfl_xor(m,o,64));
        float e0 = __expf(f0-m), e1 = __expf(f1-m);
        float ssum = e0+e1;
        #pragma unroll
        for (int o=32;o;o>>=1) ssum += __shfl_xor(ssum,o,64);
        float inv = 1.f/ssum;
        a0 += e0*inv; a1 += e1*inv;
      }
      sm.sv.part[w][l] = a0; sm.sv.part[w][l+64] = a1;
    }
    __syncthreads();
    if (t < CD){
      float s = 0.f;
      #pragma unroll
      for (int w=0;w<8;++w) s += sm.sv.part[w][t];
      sm.sv.cfs[t] = s;
    }
    __syncthreads();
    // ---- GEMV1: thread = (c2:64, kg:8)
    {
      int c2 = (t&63)*2, kg = t>>6;
      int i0 = kg*16;
      float a0 = 0.f, a1 = 0.f;
      if (fl){
        const ushort_t* W = (const ushort_t*)sp.p[1];
        #pragma unroll 4
        for (int i=i0; i<i0+16; ++i){
          unsigned w = *(const unsigned*)(W + (size_t)i*CD + c2);
          float cfv = sm.sv.cfs[i];
          a0 += unlo(w)*cfv; a1 += unhi(w)*cfv;
        }
      } else {
        const float* W = (const float*)sp.p[1];
        #pragma unroll 4
        for (int i=i0; i<i0+16; ++i){
          float2 w = *(const float2*)(W + (size_t)i*CD + c2);
          float cfv = sm.sv.cfs[i];
          a0 += w.x*cfv; a1 += w.y*cfv;
        }
      }
      sm.sv.gpart[kg][c2] = a0; sm.sv.gpart[kg][c2+1] = a1;
    }
    __syncthreads();
    if (t < CD){
      float s = 0.f;
      #pragma unroll
      for (int kg=0;kg<8;++kg) s += sm.sv.gpart[kg][t];
      float val = s + ldi(sp.p[2], t, fl);
      t1T[(size_t)t*NSV + sv] = val;
      atomicAdd(&tstats[t],     val);
      atomicAdd(&tstats[128+t], val*val);
    }
  } else {
    // ---- b == 511: moments + BN fold (wave-reduced, no per-lane LDS atomic storms)
    if (t < 18) sm.smom[t] = 0;
    __syncthreads();
    {
      // voxel moments
      int sacc[9] = {0,0,0,0,0,0,0,0,0};
      for (int v = t; v < NVOX; v += 512){
        int4 q = ((const int4*)idx)[v];
        sacc[0]+=q.y; sacc[1]+=q.z; sacc[2]+=q.w;
        sacc[3]+=q.y*q.y; sacc[4]+=q.z*q.z; sacc[5]+=q.w*q.w;
        sacc[6]+=q.y*q.z; sacc[7]+=q.y*q.w; sacc[8]+=q.z*q.w;
      }
      // supervoxel (cell) moments
      int um[9] = {0,0,0,0,0,0,0,0,0};
      if (t < 256){
        int4 q = ((const int4*)idx)[t*16];
        int gx=q.y>>2, gy=q.z>>2, gz=q.w>>2;
        um[0]=gx; um[1]=gy; um[2]=gz;
        um[3]=gx*gx; um[4]=gy*gy; um[5]=gz*gz;
        um[6]=gx*gy; um[7]=gx*gz; um[8]=gy*gz;
      }
      // 64-lane shuffle tree per moment, one atomic per wave per moment
      int lane = t & 63;
      #pragma unroll
      for (int i=0;i<9;++i){
        int s = sacc[i];
        int u = um[i];
        #pragma unroll
        for (int o=32;o;o>>=1){
          s += __shfl_xor(s, o, 64);
          u += __shfl_xor(u, o, 64);
        }
        if (lane == 0){
          if (s) atomicAdd(&sm.smom[9+i], s);
          if (u) atomicAdd(&sm.smom[i], u);
        }
      }
    }
    __syncthreads();
    if (t < 64){
      int* smom = sm.smom;
      double U1[3]={(double)smom[0],(double)smom[1],(double)smom[2]};
      double S1[3]={(double)smom[9],(double)smom[10],(double)smom[11]};
      double Uxx[3][3], Sxx[3][3];
      Uxx[0][0]=smom[3]; Uxx[1][1]=smom[4]; Uxx[2][2]=smom[5];
      Uxx[0][1]=Uxx[1][0]=smom[6]; Uxx[0][2]=Uxx[2][0]=smom[7]; Uxx[1][2]=Uxx[2][1]=smom[8];
      Sxx[0][0]=smom[12]; Sxx[1][1]=smom[13]; Sxx[2][2]=smom[14];
      Sxx[0][1]=Sxx[1][0]=smom[15]; Sxx[0][2]=Sxx[2][0]=smom[16]; Sxx[1][2]=Sxx[2][1]=smom[17];
      double M1[3], M2[3][3];
      for (int a=0;a<3;++a) M1[a] = 256.0*S1[a] - 4096.0*U1[a];
      for (int a=0;a<3;++a)
        for (int b2=0;b2<3;++b2)
          M2[a][b2] = 256.0*Sxx[a][b2] - S1[a]*U1[b2] - S1[b2]*U1[a] + 4096.0*Uxx[a][b2];
      double wv_[3]={(double)ldi(sp.p[7],t,fl),(double)ldi(sp.p[7],64+t,fl),(double)ldi(sp.p[7],128+t,fl)};
      double bj=(double)ldi(sp.p[8],t,fl), gj=(double)ldi(sp.p[9],t,fl), bej=(double)ldi(sp.p[10],t,fl);
      double Mw=0.0, wMw=0.0;
      for (int a=0;a<3;++a){
        Mw += M1[a]*wv_[a];
        for (int b2=0;b2<3;++b2) wMw += wv_[a]*M2[a][b2]*wv_[b2];
      }
      const double NM = 1048576.0;
      double mean = Mw/NM + bj;
      double Ey2  = wMw/NM + 2.0*bj*Mw/NM + bj*bj;
      double var  = Ey2 - mean*mean;
      double scale = gj / sqrt(var + 1e-5);
      afold_g[t]      = (float)(wv_[0]*scale);
      afold_g[64+t]   = (float)(wv_[1]*scale);
      afold_g[128+t]  = (float)(wv_[2]*scale);
      scfold_g[t]     = (float)(bj*scale + bej - mean*scale);
    }
  }
}

// ========== K6PB: 1024 blocks. b<512: pbias table (8 queries/block).
//            b in [512,1024): k6 GEMVs (role = (b-512)>>8: 0=k, 1=v).
// k6 half now reads BN stats (2 floats/channel) from tstats instead of
// re-reading all of t1T (was 128 KB/block x 512 blocks = 64 MB L2). ==========
__global__ __launch_bounds__(256) void k6pb(const float* t1T, const float* A,
    const int* idx, int* map, float* kb, float* vb,
    const float* afold_g, const float* scfold_g, float* pbias_b,
    const float* tstats)
{
  __shared__ float saf[3][64];
  __shared__ float ssc[64];
  __shared__ float w2s[64];
  __shared__ __align__(16) float e4q[64][8];
  __shared__ float xs[8], ys[8], zs[8];
  __shared__ float row[CD];
  __shared__ float cpar[2][CD];
  __shared__ float hrow[CD];
  int t = threadIdx.x, b = blockIdx.x;
  if (b < 512){
    // ---- pbias: hoisted 64-iter MLP; layout pbias_b[(b*256+s)*8 + qi]
    if (t < 64){
      saf[0][t] = afold_g[t]; saf[1][t] = afold_g[64+t]; saf[2][t] = afold_g[128+t];
      ssc[t] = scfold_g[t]; w2s[t] = A[OF_PW2+t];
    } else if (t < 72){
      int qi = t - 64;
      int4 q = ((const int4*)idx)[b*8 + qi];
      xs[qi] = (float)q.y; ys[qi] = (float)q.z; zs[qi] = (float)q.w;
    }
    __syncthreads();
    for (int e = t; e < 512; e += 256){
      int j = e & 63, qi = e >> 6;
      e4q[j][qi] = saf[0][j]*xs[qi] + saf[1][j]*ys[qi] + saf[2][j]*zs[qi];
    }
    __syncthreads();
    int4 q0 = ((const int4*)idx)[t*16];
    float ux = (float)(q0.y>>2), uy = (float)(q0.z>>2), uz = (float)(q0.w>>2);
    float pb2 = A[OF_PB2];
    float pbv[8];
    #pragma unroll
    for (int i=0;i<8;++i) pbv[i] = pb2;
    #pragma unroll 2
    for (int j=0;j<64;++j){
      float dj = ssc[j] - (saf[0][j]*ux + saf[1][j]*uy + saf[2][j]*uz);
      float wj = w2s[j];
      float4 e0 = *(const float4*)&e4q[j][0];
      float4 e1 = *(const float4*)&e4q[j][4];
      pbv[0] += fmaxf(e0.x+dj,0.f)*wj; pbv[1] += fmaxf(e0.y+dj,0.f)*wj;
      pbv[2] += fmaxf(e0.z+dj,0.f)*wj; pbv[3] += fmaxf(e0.w+dj,0.f)*wj;
      pbv[4] += fmaxf(e1.x+dj,0.f)*wj; pbv[5] += fmaxf(e1.y+dj,0.f)*wj;
      pbv[6] += fmaxf(e1.z+dj,0.f)*wj; pbv[7] += fmaxf(e1.w+dj,0.f)*wj;
    }
    float* dst = pbias_b + ((size_t)b*256 + t)*8;
    *(float4*)dst       = make_float4(pbv[0],pbv[1],pbv[2],pbv[3]);
    *(float4*)(dst + 4) = make_float4(pbv[4],pbv[5],pbv[6],pbv[7]);
    return;
  }
  // ---- k6: BN-fold + relu + cw2 + {wk|wv} projection for supervoxel s
  int role = (b - 512) >> 8, s = (b - 512) & 255;
  if (role == 0 && t >= 128 && t < 144){
    int v = s*16 + (t-128);
    int4 q = ((const int4*)idx)[v];
    map[((q.x*XD + q.y)*YD + q.z)*ZD + q.w] = v;
  }
  if (t < CD){
    float sum = tstats[t], sq = tstats[128+t];
    float mean = sum*(1.f/256.f);
    float var  = sq*(1.f/256.f) - mean*mean;
    float scv = A[OF_CG1+t]*rsqrtf(var+EPSF);
    float shv = A[OF_CBE1+t] - mean*scv;
    row[t] = fmaxf(t1T[(size_t)t*NSV + s]*scv + shv, 0.f);
  }
  __syncthreads();
  int c = t&127, half = t>>7;
  {
    const float* W = A + OF_CW2;
    float acc = 0.f;
    #pragma unroll 8
    for (int i=half*64;i<half*64+64;++i) acc += row[i]*W[i*CD+c];
    cpar[half][c] = acc;
  }
  __syncthreads();
  if (t < CD) hrow[t] = cpar[0][t]+cpar[1][t]+A[OF_CB2+t];
  __syncthreads();
  {
    const float* W = role ? (A+OF_WV) : (A+OF_WK);
    float acc = 0.f;
    #pragma unroll 8
    for (int i=half*64;i<half*64+64;++i) acc += hrow[i]*W[i*CD+c];
    cpar[half][c] = acc;
  }
  __syncthreads();
  if (t < CD){
    float v = cpar[0][t]+cpar[1][t] + (role ? A[OF_BV+t] : A[OF_BK+t]);
    if (role) vb[(size_t)s*CD+t] = v; else kb[(size_t)s*CD+t] = v;
  }
}

// ========== K9 v8: Q=8, 512 threads; waveized residual/LN tail ==========
#define CGRP(row,hh) (((hh) + ((row)>>1)) & 3)

__global__ __launch_bounds__(512, 4) void k9_attn(
    const float* A, const int* idx, const float* pbias_b,
    const float* kb, const float* vb, const float* qb,
    const void* featsrc, const int* flag, float* yb)
{
  __shared__ __align__(16) float q8s[8][CD];       // 4 KB [q][c]
  __shared__ __align__(16) float scf[NSV][32];     // 32 KB swizzled probs (4h x 8q)
  __shared__ __align__(16) float ctxT[CD*8];       // 4 KB [c][q] stride 8
  __shared__ __align__(16) float cpart[4096];      // 16 KB (PV: [o][q][c64]; wo: [kq][q][c128])
  __shared__ float rinv[64];                       // [q*8 + h]
  int t = threadIdx.x;
  int n0 = blockIdx.x*8;
  const int fl = *flag;
  if (t < 256) ((float4*)q8s)[t] = ((const float4*)(qb + (size_t)n0*CD))[t];
  int ts = t & 255, hp = t >> 8;
  // pbias for (sv=ts, all 8 queries): two aligned float4s; layout matches kpb
  const float* pbp = pbias_b + ((size_t)blockIdx.x*256 + ts)*8;
  float4 pbq0 = *(const float4*)pbp;
  float4 pbq1 = *(const float4*)(pbp + 4);
  float pb[8] = {pbq0.x,pbq0.y,pbq0.z,pbq0.w, pbq1.x,pbq1.y,pbq1.z,pbq1.w};
  // early-issue residual feature loads for the tail (wave g, lanes = channels)
  int gq = t>>6, lane = t&63;
  float fres0, fres1;
  if (fl){
    fres0 = bf2f((const ushort_t*)featsrc + (size_t)(n0+gq)*CD + lane);
    fres1 = bf2f((const ushort_t*)featsrc + (size_t)(n0+gq)*CD + lane + 64);
  } else {
    fres0 = ((const float*)featsrc)[(size_t)(n0+gq)*CD + lane];
    fres1 = ((const float*)featsrc)[(size_t)(n0+gq)*CD + lane + 64];
  }
  __syncthreads();
  const float4* krow = (const float4*)(kb + (size_t)ts*CD);
  #pragma unroll
  for (int p=0;p<2;++p){
    // ---- scores + exp: thread (ts, hp) handles hh = hp*2, hp*2+1
    {
      #pragma unroll
      for (int u=0; u<2; ++u){
        int hh = hp*2 + u;
        int h = p*4 + hh;
        float4 k0 = krow[h*4+0], k1 = krow[h*4+1], k2 = krow[h*4+2], k3 = krow[h*4+3];
        float pr[8];
        #pragma unroll
        for (int g=0; g<8; ++g){
          const float4* qg4 = (const float4*)&q8s[g][h*DHD];
          float4 qa = qg4[0], qbv = qg4[1], qc = qg4[2], qd = qg4[3];
          float dot = qa.x*k0.x + qa.y*k0.y + qa.z*k0.z + qa.w*k0.w
                    + qbv.x*k1.x + qbv.y*k1.y + qbv.z*k1.z + qbv.w*k1.w
                    + qc.x*k2.x + qc.y*k2.y + qc.z*k2.z + qc.w*k2.w
                    + qd.x*k3.x + qd.y*k3.y + qd.z*k3.z + qd.w*k3.w;
          pr[g] = __expf(dot*0.25f + pb[g]);
        }
        int c4a = (hh*2+0) ^ (ts&7);
        int c4b = (hh*2+1) ^ (ts&7);
        *(float4*)&scf[ts][c4a*4] = make_float4(pr[0],pr[1],pr[2],pr[3]);
        *(float4*)&scf[ts][c4b*4] = make_float4(pr[4],pr[5],pr[6],pr[7]);
      }
    }
    __syncthreads();
    // ---- denominators: wave w = query w (8 waves), 4 heads each
    {
      int w = t>>6;
      int qg = w>>2, j = w&3;
      #pragma unroll
      for (int hh=0; hh<4; ++hh){
        int slot = hh*2 + qg;
        float s0 = 0.f;
        #pragma unroll
        for (int k=0;k<4;++k){
          int r = lane + 64*k;
          s0 += scf[r][(slot ^ (r&7))*4 + j];
        }
        #pragma unroll
        for (int o=32;o;o>>=1) s0 += __shfl_xor(s0,o,64);
        if (lane==0) rinv[w*8 + p*4 + hh] = 1.f/s0;
      }
    }
    // ---- PV: thread (octant o = t>>6, channel c = t&63) of pass channels
    {
      int o = t>>6, c = t&63, hh = c>>4;
      const float* vcol = vb + p*64 + c;
      float a[8] = {0.f,0.f,0.f,0.f,0.f,0.f,0.f,0.f};
      int sA = hh*2+0, sB = hh*2+1;
      #pragma unroll 4
      for (int s=o*32; s<o*32+32; ++s){
        float v = vcol[(size_t)s*CD];
        float4 pvA = *(const float4*)&scf[s][(sA ^ (s&7))*4];
        float4 pvB = *(const float4*)&scf[s][(sB ^ (s&7))*4];
        a[0] += pvA.x*v; a[1] += pvA.y*v; a[2] += pvA.z*v; a[3] += pvA.w*v;
        a[4] += pvB.x*v; a[5] += pvB.y*v; a[6] += pvB.z*v; a[7] += pvB.w*v;
      }
      #pragma unroll
      for (int g=0;g<8;++g) cpart[o*512 + g*64 + c] = a[g];
    }
    __syncthreads();
    // ---- assemble: thread (q = t>>6, c = t&63) -> ctxT[(p*64+c)*8 + q]
    {
      int g = t>>6, c = t&63;
      float s = 0.f;
      #pragma unroll
      for (int o=0;o<8;++o) s += cpart[o*512 + g*64 + c];
      ctxT[(p*64+c)*8 + g] = s * rinv[g*8 + p*4 + (c>>4)];
    }
    // no barrier: next pass's scf writes are ordered after this pass's scf
    // reads by the post-PV barrier; next pass's cpart writes happen only
    // after its own post-score barrier (orders these cpart reads).
  }
  __syncthreads();
  // ---- wo: thread (kq = t>>7, c = t&127); K split in 4 quarters of 32
  {
    int kq = t>>7, c = t&127;
    const float* wo = A + OF_WO;
    float acc[8] = {0.f,0.f,0.f,0.f,0.f,0.f,0.f,0.f};
    #pragma unroll 4
    for (int i=kq*32; i<kq*32+32; ++i){
      float wv = wo[i*CD+c];
      float4 r0 = *(const float4*)&ctxT[i*8];
      float4 r1 = *(const float4*)&ctxT[i*8+4];
      acc[0]+=r0.x*wv; acc[1]+=r0.y*wv; acc[2]+=r0.z*wv; acc[3]+=r0.w*wv;
      acc[4]+=r1.x*wv; acc[5]+=r1.y*wv; acc[6]+=r1.z*wv; acc[7]+=r1.w*wv;
    }
    #pragma unroll
    for (int g=0;g<8;++g) cpart[kq*1024 + g*128 + c] = acc[g];
  }
  __syncthreads();
  // ---- waveized residual + LayerNorm: wave g = query g, lanes = channels
  {
    float x0 = cpart[gq*128 + lane]        + cpart[1024 + gq*128 + lane]
             + cpart[2048 + gq*128 + lane] + cpart[3072 + gq*128 + lane]
             + A[OF_BO+lane] + fres0;
    float x1 = cpart[gq*128 + lane+64]        + cpart[1024 + gq*128 + lane+64]
             + cpart[2048 + gq*128 + lane+64] + cpart[3072 + gq*128 + lane+64]
             + A[OF_BO+lane+64] + fres1;
    float s1 = x0+x1, s2 = x0*x0+x1*x1;
    #pragma unroll
    for (int o=32;o;o>>=1){ s1 += __shfl_xor(s1,o,64); s2 += __shfl_xor(s2,o,64); }
    float mean = s1*(1.f/128.f);
    float var  = s2*(1.f/128.f) - mean*mean;
    float rs = rsqrtf(var + EPSF);
    yb[(size_t)(n0+gq)*CD + lane]    = (x0-mean)*rs*A[OF_LNG+lane]    + A[OF_LNB+lane];
    yb[(size_t)(n0+gq)*CD + lane+64] = (x1-mean)*rs*A[OF_LNG+lane+64] + A[OF_LNB+lane+64];
  }
}

// ========== K10 v2: SubMConv3d, 8 voxels/block, 512 threads (8 waves) ==========
__global__ __launch_bounds__(512) void k10_conv(const int* idx, const int* map,
    const float* yb, const float* A, const float* wt, const int* flag, void* outv)
{
  __shared__ int sco4[8][4];
  __shared__ int jn[8][27];
  __shared__ float partial[8][8][NCD];   // 5 KB
  int t = threadIdx.x;
  int p0 = blockIdx.x*8;
  if (t < 32) ((int*)sco4)[t] = idx[4*p0 + t];
  __syncthreads();
  if (t < 216){
    int v = t/27, nb = t - v*27;
    int kd = nb/9, kh = (nb/3)%3, kw = nb%3;
    int bb = sco4[v][0];
    int nx = sco4[v][1]+kd-1, ny = sco4[v][2]+kh-1, nz = sco4[v][3]+kw-1;
    int j = -1;
    if ((unsigned)nx < XD && (unsigned)ny < YD && (unsigned)nz < ZD)
      j = map[((bb*XD+nx)*YD+ny)*ZD+nz];
    jn[v][nb] = j;
  }
  __syncthreads();
  int w = t>>6, l = t&63;
  int og = l & 3, cg = l >> 2;
  int c0 = cg*8;
  float acc[8][5];
  #pragma unroll
  for (int v=0;v<8;++v)
    #pragma unroll
    for (int oo=0;oo<5;++oo) acc[v][oo]=0.f;
  for (int nb = w; nb < 27; nb += 8){
    const float* wbase = wt + (size_t)nb*NCD*CD + c0;
    float4 wreg[10];
    #pragma unroll
    for (int oo=0;oo<5;++oo){
      wreg[oo*2]   = *(const float4*)(wbase + (size_t)(og*5+oo)*CD);
      wreg[oo*2+1] = *(const float4*)(wbase + (size_t)(og*5+oo)*CD + 4);
    }
    #pragma unroll
    for (int v=0; v<8; ++v){
      int j = jn[v][nb];
      if (j < 0) continue;
      const float4* y4 = (const float4*)(yb + (size_t)j*CD + c0);
      float4 ya = y4[0], ybb = y4[1];
      #pragma unroll
      for (int oo=0;oo<5;++oo){
        float4 wa = wreg[oo*2], wb = wreg[oo*2+1];
        acc[v][oo] += ya.x*wa.x + ya.y*wa.y + ya.z*wa.z + ya.w*wa.w
                    + ybb.x*wb.x + ybb.y*wb.y + ybb.z*wb.z + ybb.w*wb.w;
      }
    }
  }
  #pragma unroll
  for (int v=0;v<8;++v)
    #pragma unroll
    for (int oo=0;oo<5;++oo){
      float s = acc[v][oo];
      s += __shfl_xor(s, 4, 64);
      s += __shfl_xor(s, 8, 64);
      s += __shfl_xor(s, 16, 64);
      s += __shfl_xor(s, 32, 64);
      if (cg == 0) partial[w][v][og*5+oo] = s;
    }
  __syncthreads();
  if (t < 160){
    int v = t/20, o = t - v*20;
    float s = partial[0][v][o]+partial[1][v][o]+partial[2][v][o]+partial[3][v][o]
            + partial[4][v][o]+partial[5][v][o]+partial[6][v][o]+partial[7][v][o]
            + A[OF_SEGB+o];
    if (*flag) ((ushort_t*)outv)[(size_t)(p0+v)*NCD + o] = f2bf(s);
    else       ((float*)outv)[(size_t)(p0+v)*NCD + o]   = s;
  }
}

// ---------------- launch ----------------
extern "C" void kernel_launch(void* const* d_in, const int* in_sizes, int n_in,
                              void* d_out, int out_size, void* d_ws, size_t ws_size,
                              hipStream_t stream) {
  const int* idx = (const int*)d_in[0];

  char* w = (char*)d_ws;
  size_t off = 0;
  #define ALLOC(name, type, count) \
    type* name = (type*)(w + off); off += (((size_t)(count)*sizeof(type)) + 255) & ~(size_t)255;
  ALLOC(flag,   int,   64)
  ALLOC(arena,  float, ARENA_N)
  ALLOC(wt,     float, 27*NCD*CD)
  ALLOC(map,    int,   MAPN)
  ALLOC(afold,  float, 192)
  ALLOC(scfold, float, 64)
  ALLOC(t1T,    float, CD*NSV)
  ALLOC(kb,     float, NSV*CD)
  ALLOC(vbuf,   float, NSV*CD)
  ALLOC(qb,     float, NVOX*CD)
  ALLOC(yb,     float, NVOX*CD)
  ALLOC(pbias_b,float, 512*256*8)
  ALLOC(tstats, float, 256)
  #undef ALLOC
  (void)off; (void)ws_size; (void)n_in; (void)in_sizes; (void)out_size;

  SrcPtrs sp;
  for (int i=0;i<25;++i) sp.p[i] = d_in[i+1];

  hipMemsetAsync(tstats, 0, 256*sizeof(float), stream);
  kprep   <<<512, 512, 0, stream>>>(sp, idx, flag, arena, wt, map, afold, scfold, qb, t1T, tstats);
  k6pb    <<<1024, 256, 0, stream>>>(t1T, arena, idx, map, kb, vbuf, afold, scfold, pbias_b, tstats);
  k9_attn <<<NVOX/8, 512, 0, stream>>>(arena, idx, pbias_b, kb, vbuf, qb, d_in[1], flag, yb);
  k10_conv<<<NVOX/8, 512, 0, stream>>>(idx, map, yb, arena, wt, flag, d_out);
}